// Round 4
// baseline (64867.285 us; speedup 1.0000x reference)
//
#include <hip/hip_runtime.h>
#include <stdint.h>

// Problem dims
#define T_STEPS 8192
#define DIN     2048
#define HD      2048
#define G3      6144
#define EOUT    512

// Scan partition: 128 A-blocks own 16 r-cols + 16 z-cols each,
// 64 B-blocks own 32 a-cols + the h-update for those columns.
#define NA 128
#define NB 64
#define HP 1024          // h/rh broadcast: 1024 u64 pairs {tag | bf16 hi | bf16 lo}
#define SPIN_MAX (1<<20)

typedef unsigned long long u64;

__device__ __forceinline__ float bf_lo(uint32_t u){ return __uint_as_float(u << 16); }
__device__ __forceinline__ float bf_hi(uint32_t u){ return __uint_as_float(u & 0xffff0000u); }

__device__ __forceinline__ uint16_t f2bf(float v){   // RNE f32->bf16
  uint32_t x = __float_as_uint(v);
  return (uint16_t)((x + 0x7fffu + ((x >> 16) & 1u)) >> 16);
}

__device__ __forceinline__ u64 aload(const u64* p){
  return __hip_atomic_load(p, __ATOMIC_RELAXED, __HIP_MEMORY_SCOPE_AGENT);
}
__device__ __forceinline__ void astore(u64* p, u64 v){
  __hip_atomic_store(p, v, __ATOMIC_RELAXED, __HIP_MEMORY_SCOPE_AGENT);
}

// Pack a 2048 x NCOLS column slice of w_h (f32, row-major stride G3) into LDS
// in exact per-lane access order for matvec16.
template<int NCOLS>
__device__ void pack_w(uint16_t* dst, const float* __restrict__ wsrc, int col0, int tid){
  for (int idx = tid; idx < HD*NCOLS; idx += 512){
    int k  = idx / NCOLS;
    int cl = idx & (NCOLS - 1);
    uint16_t u = f2bf(wsrc[(size_t)k*G3 + col0 + cl]);
    int w4 = cl >> 2, j = cl & 3, c = k >> 7, it = (k & 127) >> 3, m = k & 7;
    dst[w4*8192 + it*512 + (c*4 + j)*8 + m] = u;
  }
}

// One wave computes 4 columns x 2048 rows: lane j=lane&3 owns a column,
// c=lane>>2 picks the 128-row chunk. Input vector in chunk-padded LDS:
// element k at (k>>7)*132 + (k&127).
__device__ __forceinline__ float matvec16(const uint16_t* Wp, const float* in_lds, int w4, int lane){
  const int c = lane >> 2;
  const uint4* wb = (const uint4*)(Wp + (size_t)w4*8192);
  const float* hb = in_lds + c*132;
  float acc = 0.f;
  #pragma unroll
  for (int it = 0; it < 16; ++it){
    uint4  w  = wb[it*64 + lane];                    // 8 bf16, ds_read_b128, conflict-free
    float4 h0 = *(const float4*)(hb + it*8);
    float4 h1 = *(const float4*)(hb + it*8 + 4);
    acc = fmaf(bf_lo(w.x), h0.x, acc);
    acc = fmaf(bf_hi(w.x), h0.y, acc);
    acc = fmaf(bf_lo(w.y), h0.z, acc);
    acc = fmaf(bf_hi(w.y), h0.w, acc);
    acc = fmaf(bf_lo(w.z), h1.x, acc);
    acc = fmaf(bf_hi(w.z), h1.y, acc);
    acc = fmaf(bf_lo(w.w), h1.z, acc);
    acc = fmaf(bf_hi(w.w), h1.w, acc);
  }
  acc += __shfl_xor(acc, 4, 64);
  acc += __shfl_xor(acc, 8, 64);
  acc += __shfl_xor(acc, 16, 64);
  acc += __shfl_xor(acc, 32, 64);
  return acc;   // every lane holds the total for its column j=lane&3
}

// Deposit a {tag | bf16 hi | bf16 lo} pair into chunk-padded LDS at cols 2P, 2P+1.
__device__ __forceinline__ void dep_pair(float* dst, int P, u64 v){
  uint32_t pay = (uint32_t)v;
  float lo = __uint_as_float((pay & 0xffffu) << 16);
  float hi = __uint_as_float(pay & 0xffff0000u);
  int col = 2*P;
  *(float2*)(dst + (col >> 7)*132 + (col & 127)) = make_float2(lo, hi);
}

// ---------------- gates GEMM: C[T,6144] = X[T,2048] @ Wi[2048,6144], fp32 ----
__global__ __launch_bounds__(256) void gates_gemm(const float* __restrict__ A,
                                                  const float* __restrict__ B,
                                                  float* __restrict__ C){
  __shared__ float As[16*132];
  __shared__ float Bs[16*132];
  const int bm = blockIdx.x / (G3/128);
  const int bn = blockIdx.x % (G3/128);
  const int row0 = bm*128, col0 = bn*128;
  const int tid = threadIdx.x;
  const int tr = tid >> 4, tc = tid & 15;
  float acc[8][8] = {};
  for (int k0 = 0; k0 < DIN; k0 += 16){
    {
      int r = tid >> 4, c = tid & 15;
      #pragma unroll
      for (int i = 0; i < 8; ++i){
        int row = r + 16*i;
        As[c*132 + row] = A[(size_t)(row0 + row)*DIN + k0 + c];
      }
    }
    {
      int kk = tid >> 7, cc = tid & 127;
      #pragma unroll
      for (int i = 0; i < 8; ++i){
        int k = kk + 2*i;
        Bs[k*132 + cc] = B[(size_t)(k0 + k)*G3 + col0 + cc];
      }
    }
    __syncthreads();
    #pragma unroll
    for (int kk = 0; kk < 16; ++kk){
      float4 a0 = *(float4*)&As[kk*132 + 8*tr];
      float4 a1 = *(float4*)&As[kk*132 + 8*tr + 4];
      float4 b0 = *(float4*)&Bs[kk*132 + 8*tc];
      float4 b1 = *(float4*)&Bs[kk*132 + 8*tc + 4];
      float av[8] = {a0.x,a0.y,a0.z,a0.w,a1.x,a1.y,a1.z,a1.w};
      float bv[8] = {b0.x,b0.y,b0.z,b0.w,b1.x,b1.y,b1.z,b1.w};
      #pragma unroll
      for (int i = 0; i < 8; ++i)
        #pragma unroll
        for (int j = 0; j < 8; ++j)
          acc[i][j] = fmaf(av[i], bv[j], acc[i][j]);
    }
    __syncthreads();
  }
  #pragma unroll
  for (int i = 0; i < 8; ++i){
    size_t off = (size_t)(row0 + 8*tr + i)*G3 + col0 + 8*tc;
    float4 v0 = {acc[i][0],acc[i][1],acc[i][2],acc[i][3]};
    float4 v1 = {acc[i][4],acc[i][5],acc[i][6],acc[i][7]};
    *(float4*)(C + off)     = v0;
    *(float4*)(C + off + 4) = v1;
  }
}

// ---------------- persistent GRU scan --------------------------------------
// h_t:  hbuf [t&1][1024]  {tag t   | 2x bf16}    (memset0 == h_0=0, tag 0)
// rh_t: rhbuf[t&1][1024]  {tag t+1 | 2x bf16}
// z_t:  zbufg[t&1][2048]  {tag t+1 | f32}        (read only by 32-col owner)
// B keeps its own 32 h columns in LDS as f32 (state path never quantized).
// One __syncthreads per step; cross-step LDS reuse ordered by tag chain.
__global__ __launch_bounds__(512) void scan_kernel(
    const float* __restrict__ gates, const float* __restrict__ w_h,
    const float* __restrict__ b,
    u64* hbuf, u64* rhbuf, u64* zbufg, float* hfinal)
{
  __shared__ __align__(16) unsigned char smem[148800];
  uint16_t* W0   = (uint16_t*)(smem);             // A: Wr(16c). B: Wa(32c, 128KB)
  uint16_t* W1   = (uint16_t*)(smem + 65536);     // A: Wz(16c)
  float*    vecb = (float*)(smem + 131072);       // [2][2112] h (A) / rh (B) staging
  float*    gx   = (float*)(smem + 147968);       // [2][32] x-gates (+bias)
  float*    zsl  = (float*)(smem + 148224);       // [2][32] z slice (B)
  float*    hloc = (float*)(smem + 148480);       // [2][32] local f32 h (B)
  volatile int* deadp = (volatile int*)(smem + 148736);

  const int tid  = threadIdx.x;
  const int lane = tid & 63;
  const int wid  = tid >> 6;
  const bool isA = blockIdx.x < NA;
  const int  g   = isA ? (int)blockIdx.x : (int)blockIdx.x - NA;

  if (isA) {
    pack_w<16>(W0, w_h, 2048 + 16*g, tid);        // r columns
    pack_w<16>(W1, w_h, 16*g, tid);               // z columns
  } else {
    pack_w<32>(W0, w_h, 4096 + 32*g, tid);        // a columns
    if (tid < 64) hloc[tid] = 0.f;                // h_0 = 0
  }
  if (tid == 0) *deadp = 0;

  int   gcol = -1;
  float bias = 0.f;
  if (isA) { if (tid < 16)      gcol = 16*g + tid;              // z gate
             else if (tid < 32) gcol = 2048 + 16*g + (tid-16); } // r gate
  else     { if (tid < 32)      gcol = 4096 + 32*g + tid; }      // a gate
  if (gcol >= 0) { bias = b[gcol]; gx[tid & 31] = gates[gcol] + bias; }
  __syncthreads();

  for (int t = 0; t < T_STEPS; ++t){
    const int par = t & 1;
    float gxn = 0.f;
    if (gcol >= 0){
      int tn = (t + 1 < T_STEPS) ? t + 1 : t;
      gxn = gates[(size_t)tn*G3 + gcol] + bias;
    }

    if (isA){
      // ---- poll h_t (tag >= t): 2 pairs per thread ----
      const u64* src = hbuf + (size_t)par*HP;
      u64 v0, v1; int spins = 0;
      for(;;){
        v0 = aload(src + tid);
        v1 = aload(src + tid + 512);
        if ((uint32_t)(v0 >> 32) >= (uint32_t)t &&
            (uint32_t)(v1 >> 32) >= (uint32_t)t) break;
        if (*deadp) break;
        if (++spins > SPIN_MAX){ *deadp = 1; break; }
        __builtin_amdgcn_s_sleep(1);
      }
      float* hl = vecb + par*2112;
      dep_pair(hl, tid, v0);
      dep_pair(hl, tid + 512, v1);
      __syncthreads();
      if (*deadp) break;

      const bool isR = (wid < 4);
      const int  w4  = wid & 3;
      float acc = matvec16(isR ? W0 : W1, hl, w4, lane);
      int cl = 4*w4 + (lane & 3);
      if (isR){
        float pre = acc + gx[par*32 + 16 + cl];
        float r = 1.f / (1.f + __expf(-pre));
        int col = 16*g + cl;
        float rh = r * hl[(col >> 7)*132 + (col & 127)];
        float other = __shfl_xor(rh, 1);
        if (lane == 0 || lane == 2){
          u64 pv = ((u64)(uint32_t)(t + 1) << 32)
                 | ((u64)f2bf(other) << 16) | (u64)f2bf(rh);
          astore(rhbuf + (size_t)par*HP + 8*g + 2*w4 + (lane >> 1), pv);
        }
      } else {
        float pre = acc + gx[par*32 + cl];
        float z = 1.f / (1.f + __expf(-pre));
        if (lane < 4){
          u64 pv = ((u64)(uint32_t)(t + 1) << 32) | (u64)__float_as_uint(z);
          astore(zbufg + (size_t)par*2048 + 16*g + cl, pv);
        }
      }
      if (gcol >= 0) gx[(par^1)*32 + (tid & 31)] = gxn;
    } else {
      // ---- poll rh_t (tag >= t+1, 2 pairs/thread) + z slice (tid<32) ----
      const u64* src = rhbuf + (size_t)par*HP;
      const u64* zs  = zbufg + (size_t)par*2048 + 32*g;
      const bool needz = (tid < 32);
      u64 v0, v1, vz = 0; int spins = 0;
      const uint32_t want = (uint32_t)(t + 1);
      for(;;){
        v0 = aload(src + tid);
        v1 = aload(src + tid + 512);
        if (needz) vz = aload(zs + tid);
        bool ok = (uint32_t)(v0 >> 32) >= want &&
                  (uint32_t)(v1 >> 32) >= want &&
                  (!needz || (uint32_t)(vz >> 32) >= want);
        if (ok) break;
        if (*deadp) break;
        if (++spins > SPIN_MAX){ *deadp = 1; break; }
        __builtin_amdgcn_s_sleep(1);
      }
      float* rl = vecb + par*2112;
      dep_pair(rl, tid, v0);
      dep_pair(rl, tid + 512, v1);
      if (needz) zsl[par*32 + tid] = __uint_as_float((uint32_t)vz);
      __syncthreads();
      if (*deadp) break;

      float acc = matvec16(W0, rl, wid, lane);     // a pre-activation
      int cl = 4*wid + (lane & 3);
      float pre = acc + gx[par*32 + cl];
      float e = __expf(2.f*pre);
      float a = 1.f - 2.f/(1.f + e);                // tanh, saturation-safe
      float z = zsl[par*32 + cl];
      float hold = hloc[par*32 + cl];
      float hnew = hold + z*(a - hold);             // (1-z)h + z*a
      float other = __shfl_xor(hnew, 1);
      if (lane < 4) hloc[(par^1)*32 + cl] = hnew;
      if (lane == 0 || lane == 2){
        u64 pv = ((u64)(uint32_t)(t + 1) << 32)
               | ((u64)f2bf(other) << 16) | (u64)f2bf(hnew);
        astore(hbuf + (size_t)((t+1)&1)*HP + 16*g + 2*wid + (lane >> 1), pv);
      }
      if (gcol >= 0) gx[(par^1)*32 + (tid & 31)] = gxn;
    }
  }

  // T even -> final h in hloc[0]; publish f32 (kernel-boundary flush covers it)
  if (!isA && tid < 32) hfinal[32*g + tid] = hloc[0*32 + tid];
}

// ---------------- out = h_final @ w_out + b_out ----------------------------
__global__ __launch_bounds__(1024) void out_proj(const float* __restrict__ hfin,
                                                 const float* __restrict__ w_out,
                                                 const float* __restrict__ b_out,
                                                 float* __restrict__ out){
  __shared__ float red[16][80];
  const int g  = blockIdx.x;
  const int cl = threadIdx.x & 63;
  const int kc = threadIdx.x >> 6;        // 0..15
  const int col = 64*g + cl;
  float acc = 0.f;
  for (int k = kc*128; k < kc*128 + 128; ++k)
    acc = fmaf(hfin[k], w_out[(size_t)k*EOUT + col], acc);
  red[kc][cl] = acc;
  __syncthreads();
  if (kc == 0){
    float s = 0.f;
    #pragma unroll
    for (int q = 0; q < 16; ++q) s += red[q][cl];
    out[col] = s + b_out[col];
  }
}

extern "C" void kernel_launch(void* const* d_in, const int* in_sizes, int n_in,
                              void* d_out, int out_size, void* d_ws, size_t ws_size,
                              hipStream_t stream) {
  const float* x     = (const float*)d_in[0];   // (8192, 2048)
  const float* w_i   = (const float*)d_in[1];   // (2048, 6144)
  const float* w_h   = (const float*)d_in[2];   // (2048, 6144)
  const float* b     = (const float*)d_in[3];   // (6144,)
  const float* w_out = (const float*)d_in[4];   // (2048, 512)
  const float* b_out = (const float*)d_in[5];   // (512,)
  float* out = (float*)d_out;

  // Workspace: gates f32 (201.3MB) | hbuf u64[2][1024] | rhbuf u64[2][1024]
  //            | zbufg u64[2][2048] | hfinal f32[2048]
  float* gates  = (float*)d_ws;
  u64*   hbuf   = (u64*)(gates + (size_t)T_STEPS * G3);
  u64*   rhbuf  = hbuf + 2*HP;
  u64*   zbufg  = rhbuf + 2*HP;
  float* hfinal = (float*)(zbufg + 2*2048);
  (void)in_sizes; (void)n_in; (void)out_size; (void)ws_size;

  // zero tagged buffers: h_0=0 tag0 ready; rh/z never ready until written
  hipMemsetAsync(hbuf, 0, (size_t)(2*HP + 2*HP + 2*2048)*sizeof(u64), stream);

  gates_gemm<<<dim3((T_STEPS/128)*(G3/128)), dim3(256), 0, stream>>>(x, w_i, gates);

  const float* gates_c = gates;
  void* kargs[7];
  kargs[0] = (void*)&gates_c;
  kargs[1] = (void*)&w_h;
  kargs[2] = (void*)&b;
  kargs[3] = (void*)&hbuf;
  kargs[4] = (void*)&rhbuf;
  kargs[5] = (void*)&zbufg;
  kargs[6] = (void*)&hfinal;
  hipLaunchCooperativeKernel((void*)scan_kernel, dim3(NA + NB), dim3(512), kargs, 0u, stream);

  out_proj<<<dim3(EOUT/64), dim3(1024), 0, stream>>>(hfinal, w_out, b_out, out);
}

// Round 5
// 34704.510 us; speedup vs baseline: 1.8691x; 1.8691x over previous
//
#include <hip/hip_runtime.h>
#include <stdint.h>

// Problem dims
#define T_STEPS 8192
#define DIN     2048
#define HD      2048
#define G3      6144
#define EOUT    512

// Scan partition: 128 A-blocks own 16 r-cols + 16 z-cols each,
// 64 B-blocks own 32 a-cols + the h-update for those columns.
#define NA 128
#define NB 64
#define HP 1024          // h/rh broadcast: 1024 u64 pairs {tag | bf16 hi | bf16 lo}
#define SPIN_MAX (1<<20)

typedef unsigned long long u64;
typedef __attribute__((ext_vector_type(8))) __bf16 bf16x8;
typedef __attribute__((ext_vector_type(8))) unsigned short u16x8;
typedef __attribute__((ext_vector_type(4))) float f32x4;

__device__ __forceinline__ uint16_t f2bf(float v){   // RNE f32->bf16
  uint32_t x = __float_as_uint(v);
  return (uint16_t)((x + 0x7fffu + ((x >> 16) & 1u)) >> 16);
}

__device__ __forceinline__ u64 aload(const u64* p){
  return __hip_atomic_load(p, __ATOMIC_RELAXED, __HIP_MEMORY_SCOPE_AGENT);
}
__device__ __forceinline__ void astore(u64* p, u64 v){
  __hip_atomic_store(p, v, __ATOMIC_RELAXED, __HIP_MEMORY_SCOPE_AGENT);
}

// A-fragment loader: lane supplies A[m = lane&15][k = kb + j], j=0..7,
// from w_h column `col` (f32, row-major, stride G3), converted to bf16.
__device__ __forceinline__ bf16x8 load_afrag(const float* __restrict__ w, int col, int kb){
  u16x8 r;
  #pragma unroll
  for (int j = 0; j < 8; ++j)
    r[j] = f2bf(w[(size_t)(kb + j)*G3 + col]);
  return __builtin_bit_cast(bf16x8, r);
}

// ---------------- gates GEMM: C[T,6144] = X[T,2048] @ Wi[2048,6144], fp32 ----
__global__ __launch_bounds__(256) void gates_gemm(const float* __restrict__ A,
                                                  const float* __restrict__ B,
                                                  float* __restrict__ C){
  __shared__ float As[16*132];
  __shared__ float Bs[16*132];
  const int bm = blockIdx.x / (G3/128);
  const int bn = blockIdx.x % (G3/128);
  const int row0 = bm*128, col0 = bn*128;
  const int tid = threadIdx.x;
  const int tr = tid >> 4, tc = tid & 15;
  float acc[8][8] = {};
  for (int k0 = 0; k0 < DIN; k0 += 16){
    {
      int r = tid >> 4, c = tid & 15;
      #pragma unroll
      for (int i = 0; i < 8; ++i){
        int row = r + 16*i;
        As[c*132 + row] = A[(size_t)(row0 + row)*DIN + k0 + c];
      }
    }
    {
      int kk = tid >> 7, cc = tid & 127;
      #pragma unroll
      for (int i = 0; i < 8; ++i){
        int k = kk + 2*i;
        Bs[k*132 + cc] = B[(size_t)(k0 + k)*G3 + col0 + cc];
      }
    }
    __syncthreads();
    #pragma unroll
    for (int kk = 0; kk < 16; ++kk){
      float4 a0 = *(float4*)&As[kk*132 + 8*tr];
      float4 a1 = *(float4*)&As[kk*132 + 8*tr + 4];
      float4 b0 = *(float4*)&Bs[kk*132 + 8*tc];
      float4 b1 = *(float4*)&Bs[kk*132 + 8*tc + 4];
      float av[8] = {a0.x,a0.y,a0.z,a0.w,a1.x,a1.y,a1.z,a1.w};
      float bv[8] = {b0.x,b0.y,b0.z,b0.w,b1.x,b1.y,b1.z,b1.w};
      #pragma unroll
      for (int i = 0; i < 8; ++i)
        #pragma unroll
        for (int j = 0; j < 8; ++j)
          acc[i][j] = fmaf(av[i], bv[j], acc[i][j]);
    }
    __syncthreads();
  }
  #pragma unroll
  for (int i = 0; i < 8; ++i){
    size_t off = (size_t)(row0 + 8*tr + i)*G3 + col0 + 8*tc;
    float4 v0 = {acc[i][0],acc[i][1],acc[i][2],acc[i][3]};
    float4 v1 = {acc[i][4],acc[i][5],acc[i][6],acc[i][7]};
    *(float4*)(C + off)     = v0;
    *(float4*)(C + off + 4) = v1;
  }
}

// ---------------- persistent GRU scan (MFMA, register-resident weights) -----
// Broadcast protocol identical to round 4 (tagged bf16 pairs, relaxed agent
// atomics, parity double-buffer, monotone-tag safety):
//   h_t:  hbuf [t&1][1024]  {tag t   | 2x bf16}   (memset0 == h_0=0, tag 0)
//   rh_t: rhbuf[t&1][1024]  {tag t+1 | 2x bf16}
//   z_t:  zbufg[t&1][2048]  {tag t+1 | f32}
// Matvec engine: each wave owns k-slice [wid*256, wid*256+256); weights for
// the block's 32 columns are persistent MFMA A-fragments (64 VGPR/lane).
// One 16x16x32 MFMA per (group, kstep) with B = h-slice replicated over n;
// D column n=0 (lanes 0/16/32/48) holds the partial dots. Cross-wave
// reduction via a tiny LDS buffer. Per-step LDS traffic ~30 wave-instrs
// (vs 384 ds_read_b128 in the LDS-weight version).
__global__ __launch_bounds__(512) void scan_kernel(
    const float* __restrict__ gates, const float* __restrict__ w_h,
    const float* __restrict__ b,
    u64* hbuf, u64* rhbuf, u64* zbufg, float* hfinal)
{
  __shared__ uint32_t vpack[2][1024];  // packed bf16 pairs: h (A-blocks) / rh (B-blocks)
  __shared__ float    red[32*9];       // [colLocal][wid] partial dots, pad 9
  __shared__ float    gx[2][32];       // x-gates (+bias), prefetched
  __shared__ float    zsl[2][32];      // z slice (B-blocks)
  __shared__ float    hloc[2][32];     // local f32 h state (B-blocks)
  __shared__ int      dead;
  volatile int* deadp = &dead;

  const int tid  = threadIdx.x;
  const int lane = tid & 63;
  const int wid  = tid >> 6;
  const bool isA = blockIdx.x < NA;
  const int  g   = isA ? (int)blockIdx.x : (int)blockIdx.x - NA;

  // Column bases: A: group0 = r (2048+16g), group1 = z (16g).
  //               B: group0 = a (4096+32g), group1 = a (+16).
  int colG0, colG1;
  if (isA){ colG0 = 2048 + 16*g + (lane & 15); colG1 = 16*g + (lane & 15); }
  else    { colG0 = 4096 + 32*g + (lane & 15); colG1 = colG0 + 16; }

  // Persistent weight fragments: aw[group][kstep], k = wid*256 + s*32 + (lane>>4)*8 + j
  bf16x8 aw0[8], aw1[8];
  {
    const int kb0 = wid*256 + ((lane >> 4) << 3);
    #pragma unroll
    for (int s = 0; s < 8; ++s){
      aw0[s] = load_afrag(w_h, colG0, kb0 + s*32);
      aw1[s] = load_afrag(w_h, colG1, kb0 + s*32);
    }
  }

  if (tid == 0) *deadp = 0;
  if (tid < 64) ((float*)hloc)[tid] = 0.f;

  int   gcol = -1;
  float bias = 0.f;
  if (isA) { if (tid < 16)      gcol = 2048 + 16*g + tid;        // r gate
             else if (tid < 32) gcol = 16*g + (tid - 16); }      // z gate
  else     { if (tid < 32)      gcol = 4096 + 32*g + tid; }      // a gate
  if (gcol >= 0) { bias = b[gcol]; gx[0][tid] = gates[gcol] + bias; }
  __syncthreads();

  for (int t = 0; t < T_STEPS; ++t){
    const int par = t & 1;
    float gxn = 0.f;
    if (gcol >= 0){
      int tn = (t + 1 < T_STEPS) ? t + 1 : t;
      gxn = gates[(size_t)tn*G3 + gcol] + bias;
    }

    // ---- poll + deposit (packed bf16 pairs straight into LDS) ----
    if (isA){
      const u64* src = hbuf + (size_t)par*HP;
      u64 v0, v1; int spins = 0;
      const uint32_t want = (uint32_t)t;
      for(;;){
        v0 = aload(src + tid);
        v1 = aload(src + tid + 512);
        if ((uint32_t)(v0 >> 32) >= want && (uint32_t)(v1 >> 32) >= want) break;
        if (*deadp) break;
        if (++spins > SPIN_MAX){ *deadp = 1; break; }
        __builtin_amdgcn_s_sleep(1);
      }
      vpack[par][tid]       = (uint32_t)v0;
      vpack[par][tid + 512] = (uint32_t)v1;
    } else {
      const u64* src = rhbuf + (size_t)par*HP;
      const u64* zs  = zbufg + (size_t)par*2048 + 32*g;
      const bool needz = (tid < 32);
      u64 v0, v1, vz = 0; int spins = 0;
      const uint32_t want = (uint32_t)(t + 1);
      for(;;){
        v0 = aload(src + tid);
        v1 = aload(src + tid + 512);
        if (needz) vz = aload(zs + tid);
        bool ok = (uint32_t)(v0 >> 32) >= want &&
                  (uint32_t)(v1 >> 32) >= want &&
                  (!needz || (uint32_t)(vz >> 32) >= want);
        if (ok) break;
        if (*deadp) break;
        if (++spins > SPIN_MAX){ *deadp = 1; break; }
        __builtin_amdgcn_s_sleep(1);
      }
      vpack[par][tid]       = (uint32_t)v0;
      vpack[par][tid + 512] = (uint32_t)v1;
      if (needz) zsl[par][tid] = __uint_as_float((uint32_t)vz);
    }
    __syncthreads();
    if (*deadp) break;

    // ---- matvec: 16 MFMAs per wave, B-frag = broadcast vector slice ----
    {
      const uint32_t* vp = &vpack[par][wid*128];   // this wave's 256-elem k-slice
      const int boff = (lane >> 4) << 2;           // u32 idx of lane's 8 bf16
      f32x4 acc0 = {0.f,0.f,0.f,0.f}, acc1 = {0.f,0.f,0.f,0.f};
      #pragma unroll
      for (int s = 0; s < 8; ++s){
        uint4 bu = *(const uint4*)(vp + s*16 + boff);
        bf16x8 bf = __builtin_bit_cast(bf16x8, bu);
        acc0 = __builtin_amdgcn_mfma_f32_16x16x32_bf16(aw0[s], bf, acc0, 0, 0, 0);
        acc1 = __builtin_amdgcn_mfma_f32_16x16x32_bf16(aw1[s], bf, acc1, 0, 0, 0);
      }
      if ((lane & 15) == 0){                       // D[:,0]: m = (lane>>4)*4 + r
        int mb = (lane >> 4) << 2;
        #pragma unroll
        for (int r = 0; r < 4; ++r){
          red[(mb + r)*9 + wid]        = acc0[r];
          red[(16 + mb + r)*9 + wid]   = acc1[r];
        }
      }
    }
    __syncthreads();

    // ---- finalize: threads 0..31 own the block's 32 columns ----
    if (tid < 32){
      float acc = 0.f;
      #pragma unroll
      for (int w = 0; w < 8; ++w) acc += red[tid*9 + w];
      float pre = acc + gx[par][tid];

      if (isA){
        if (tid < 16){                             // r -> publish rh (bf16 pair)
          float r = 1.f / (1.f + __expf(-pre));
          int hcol = 16*g + tid;
          uint32_t hp = vpack[par][hcol >> 1];
          float hval = __uint_as_float((hcol & 1) ? (hp & 0xffff0000u) : (hp << 16));
          float rh = r * hval;
          float other = __shfl_xor(rh, 1);
          if (!(tid & 1)){
            u64 pv = ((u64)(uint32_t)(t + 1) << 32)
                   | ((u64)f2bf(other) << 16) | (u64)f2bf(rh);
            astore(rhbuf + (size_t)par*HP + ((16*g + tid) >> 1), pv);
          }
        } else {                                   // z -> publish f32
          float z = 1.f / (1.f + __expf(-pre));
          u64 pv = ((u64)(uint32_t)(t + 1) << 32) | (u64)__float_as_uint(z);
          astore(zbufg + (size_t)par*2048 + 16*g + (tid - 16), pv);
        }
      } else {                                     // a -> h update -> publish h
        float e = __expf(2.f*pre);
        float a = 1.f - 2.f/(1.f + e);             // tanh, saturation-safe
        float z = zsl[par][tid];
        float hold = hloc[par][tid];
        float hnew = hold + z*(a - hold);          // (1-z)h + z*a
        hloc[par ^ 1][tid] = hnew;
        float other = __shfl_xor(hnew, 1);
        if (!(tid & 1)){
          u64 pv = ((u64)(uint32_t)(t + 1) << 32)
                 | ((u64)f2bf(other) << 16) | (u64)f2bf(hnew);
          astore(hbuf + (size_t)((t+1)&1)*HP + ((32*g + tid) >> 1), pv);
        }
      }
      gx[par ^ 1][tid] = gxn;
    }
  }

  // T even -> final h in hloc[0]; kernel-boundary flush makes it visible
  if (!isA && tid < 32) hfinal[32*g + tid] = hloc[0][tid];
}

// ---------------- out = h_final @ w_out + b_out ----------------------------
__global__ __launch_bounds__(1024) void out_proj(const float* __restrict__ hfin,
                                                 const float* __restrict__ w_out,
                                                 const float* __restrict__ b_out,
                                                 float* __restrict__ out){
  __shared__ float red[16][80];
  const int g  = blockIdx.x;
  const int cl = threadIdx.x & 63;
  const int kc = threadIdx.x >> 6;        // 0..15
  const int col = 64*g + cl;
  float acc = 0.f;
  for (int k = kc*128; k < kc*128 + 128; ++k)
    acc = fmaf(hfin[k], w_out[(size_t)k*EOUT + col], acc);
  red[kc][cl] = acc;
  __syncthreads();
  if (kc == 0){
    float s = 0.f;
    #pragma unroll
    for (int q = 0; q < 16; ++q) s += red[q][cl];
    out[col] = s + b_out[col];
  }
}

extern "C" void kernel_launch(void* const* d_in, const int* in_sizes, int n_in,
                              void* d_out, int out_size, void* d_ws, size_t ws_size,
                              hipStream_t stream) {
  const float* x     = (const float*)d_in[0];   // (8192, 2048)
  const float* w_i   = (const float*)d_in[1];   // (2048, 6144)
  const float* w_h   = (const float*)d_in[2];   // (2048, 6144)
  const float* b     = (const float*)d_in[3];   // (6144,)
  const float* w_out = (const float*)d_in[4];   // (2048, 512)
  const float* b_out = (const float*)d_in[5];   // (512,)
  float* out = (float*)d_out;

  // Workspace: gates f32 (201.3MB) | hbuf u64[2][1024] | rhbuf u64[2][1024]
  //            | zbufg u64[2][2048] | hfinal f32[2048]
  float* gates  = (float*)d_ws;
  u64*   hbuf   = (u64*)(gates + (size_t)T_STEPS * G3);
  u64*   rhbuf  = hbuf + 2*HP;
  u64*   zbufg  = rhbuf + 2*HP;
  float* hfinal = (float*)(zbufg + 2*2048);
  (void)in_sizes; (void)n_in; (void)out_size; (void)ws_size;

  // zero tagged buffers: h_0=0 tag0 ready; rh/z never ready until written
  hipMemsetAsync(hbuf, 0, (size_t)(2*HP + 2*HP + 2*2048)*sizeof(u64), stream);

  gates_gemm<<<dim3((T_STEPS/128)*(G3/128)), dim3(256), 0, stream>>>(x, w_i, gates);

  const float* gates_c = gates;
  void* kargs[7];
  kargs[0] = (void*)&gates_c;
  kargs[1] = (void*)&w_h;
  kargs[2] = (void*)&b;
  kargs[3] = (void*)&hbuf;
  kargs[4] = (void*)&rhbuf;
  kargs[5] = (void*)&zbufg;
  kargs[6] = (void*)&hfinal;
  hipLaunchCooperativeKernel((void*)scan_kernel, dim3(NA + NB), dim3(512), kargs, 0u, stream);

  out_proj<<<dim3(EOUT/64), dim3(1024), 0, stream>>>(hfinal, w_out, b_out, out);
}

// Round 6
// 32321.497 us; speedup vs baseline: 2.0069x; 1.0737x over previous
//
#include <hip/hip_runtime.h>
#include <stdint.h>

// Problem dims
#define T_STEPS 8192
#define DIN     2048
#define HD      2048
#define G3      6144
#define EOUT    512

// Scan partition: 128 A-blocks own 16 r-cols + 16 z-cols each,
// 64 B-blocks own 32 a-cols + the h-update for those columns.
#define NA 128
#define NB 64
#define HP 1024          // h/rh broadcast: 1024 u64 pairs {tag | bf16 hi | bf16 lo}
#define NREP 8           // broadcast replicas (cuts LLC same-line fan-out 8x)
#define SPIN_MAX (1<<20)

typedef unsigned long long u64;
typedef __attribute__((ext_vector_type(8))) __bf16 bf16x8;
typedef __attribute__((ext_vector_type(8))) unsigned short u16x8;
typedef __attribute__((ext_vector_type(4))) float f32x4;

__device__ __forceinline__ uint16_t f2bf(float v){   // RNE f32->bf16
  uint32_t x = __float_as_uint(v);
  return (uint16_t)((x + 0x7fffu + ((x >> 16) & 1u)) >> 16);
}

__device__ __forceinline__ u64 aload(const u64* p){
  return __hip_atomic_load(p, __ATOMIC_RELAXED, __HIP_MEMORY_SCOPE_AGENT);
}
__device__ __forceinline__ void astore(u64* p, u64 v){
  __hip_atomic_store(p, v, __ATOMIC_RELAXED, __HIP_MEMORY_SCOPE_AGENT);
}

// A-fragment loader: lane supplies A[m = lane&15][k = kb + j], j=0..7,
// from w_h column `col` (f32, row-major, stride G3), converted to bf16.
__device__ __forceinline__ bf16x8 load_afrag(const float* __restrict__ w, int col, int kb){
  u16x8 r;
  #pragma unroll
  for (int j = 0; j < 8; ++j)
    r[j] = f2bf(w[(size_t)(kb + j)*G3 + col]);
  return __builtin_bit_cast(bf16x8, r);
}

// ---------------- gates GEMM: C[T,6144] = X[T,2048] @ Wi[2048,6144], fp32 ----
__global__ __launch_bounds__(256) void gates_gemm(const float* __restrict__ A,
                                                  const float* __restrict__ B,
                                                  float* __restrict__ C){
  __shared__ float As[16*132];
  __shared__ float Bs[16*132];
  const int bm = blockIdx.x / (G3/128);
  const int bn = blockIdx.x % (G3/128);
  const int row0 = bm*128, col0 = bn*128;
  const int tid = threadIdx.x;
  const int tr = tid >> 4, tc = tid & 15;
  float acc[8][8] = {};
  for (int k0 = 0; k0 < DIN; k0 += 16){
    {
      int r = tid >> 4, c = tid & 15;
      #pragma unroll
      for (int i = 0; i < 8; ++i){
        int row = r + 16*i;
        As[c*132 + row] = A[(size_t)(row0 + row)*DIN + k0 + c];
      }
    }
    {
      int kk = tid >> 7, cc = tid & 127;
      #pragma unroll
      for (int i = 0; i < 8; ++i){
        int k = kk + 2*i;
        Bs[k*132 + cc] = B[(size_t)(k0 + k)*G3 + col0 + cc];
      }
    }
    __syncthreads();
    #pragma unroll
    for (int kk = 0; kk < 16; ++kk){
      float4 a0 = *(float4*)&As[kk*132 + 8*tr];
      float4 a1 = *(float4*)&As[kk*132 + 8*tr + 4];
      float4 b0 = *(float4*)&Bs[kk*132 + 8*tc];
      float4 b1 = *(float4*)&Bs[kk*132 + 8*tc + 4];
      float av[8] = {a0.x,a0.y,a0.z,a0.w,a1.x,a1.y,a1.z,a1.w};
      float bv[8] = {b0.x,b0.y,b0.z,b0.w,b1.x,b1.y,b1.z,b1.w};
      #pragma unroll
      for (int i = 0; i < 8; ++i)
        #pragma unroll
        for (int j = 0; j < 8; ++j)
          acc[i][j] = fmaf(av[i], bv[j], acc[i][j]);
    }
    __syncthreads();
  }
  #pragma unroll
  for (int i = 0; i < 8; ++i){
    size_t off = (size_t)(row0 + 8*tr + i)*G3 + col0 + 8*tc;
    float4 v0 = {acc[i][0],acc[i][1],acc[i][2],acc[i][3]};
    float4 v1 = {acc[i][4],acc[i][5],acc[i][6],acc[i][7]};
    *(float4*)(C + off)     = v0;
    *(float4*)(C + off + 4) = v1;
  }
}

// ---------------- persistent GRU scan (MFMA weights, replicated broadcast) --
// h_t:  hbuf [rep][t&1][1024]  {tag t   | 2x bf16}   (memset0 == h_0=0, tag 0)
// rh_t: rhbuf[rep][t&1][1024]  {tag t+1 | 2x bf16}
// z_t:  zbufg[t&1][2048]       {tag t+1 | f32}       (single consumer/line)
// Producers store all NREP replicas (fire-and-forget); consumer block polls
// replica (blockIdx&7) only -> LLC same-line fan-out cut 8x.
__global__ __launch_bounds__(512) void scan_kernel(
    const float* __restrict__ gates, const float* __restrict__ w_h,
    const float* __restrict__ b,
    u64* hbuf, u64* rhbuf, u64* zbufg, float* hfinal)
{
  __shared__ uint32_t vpack[2][1024];  // packed bf16 pairs: h (A-blocks) / rh (B-blocks)
  __shared__ float    red[32*9];       // [colLocal][wid] partial dots, pad 9
  __shared__ float    gx[2][32];       // x-gates (+bias), prefetched
  __shared__ float    zsl[2][32];      // z slice (B-blocks)
  __shared__ float    hloc[2][32];     // local f32 h state (B-blocks)
  __shared__ int      dead;
  volatile int* deadp = &dead;

  const int tid  = threadIdx.x;
  const int lane = tid & 63;
  const int wid  = tid >> 6;
  const bool isA = blockIdx.x < NA;
  const int  g   = isA ? (int)blockIdx.x : (int)blockIdx.x - NA;
  const int  rep = blockIdx.x & (NREP - 1);

  // Column bases: A: group0 = r (2048+16g), group1 = z (16g).
  //               B: group0 = a (4096+32g), group1 = a (+16).
  int colG0, colG1;
  if (isA){ colG0 = 2048 + 16*g + (lane & 15); colG1 = 16*g + (lane & 15); }
  else    { colG0 = 4096 + 32*g + (lane & 15); colG1 = colG0 + 16; }

  // Persistent weight fragments: aw[group][kstep], k = wid*256 + s*32 + (lane>>4)*8 + j
  bf16x8 aw0[8], aw1[8];
  {
    const int kb0 = wid*256 + ((lane >> 4) << 3);
    #pragma unroll
    for (int s = 0; s < 8; ++s){
      aw0[s] = load_afrag(w_h, colG0, kb0 + s*32);
      aw1[s] = load_afrag(w_h, colG1, kb0 + s*32);
    }
  }

  if (tid == 0) *deadp = 0;
  if (tid < 64) ((float*)hloc)[tid] = 0.f;

  int   gcol = -1;
  float bias = 0.f;
  if (isA) { if (tid < 16)      gcol = 2048 + 16*g + tid;        // r gate
             else if (tid < 32) gcol = 16*g + (tid - 16); }      // z gate
  else     { if (tid < 32)      gcol = 4096 + 32*g + tid; }      // a gate
  if (gcol >= 0) { bias = b[gcol]; gx[0][tid] = gates[gcol] + bias; }
  __syncthreads();

  for (int t = 0; t < T_STEPS; ++t){
    const int par = t & 1;

    // ---- poll + deposit (packed bf16 pairs straight into LDS) ----
    if (isA){
      const u64* src = hbuf + ((size_t)(rep*2 + par))*HP;
      u64 v0, v1; int spins = 0;
      const uint32_t want = (uint32_t)t;
      for(;;){
        v0 = aload(src + tid);
        v1 = aload(src + tid + 512);
        if ((uint32_t)(v0 >> 32) >= want && (uint32_t)(v1 >> 32) >= want) break;
        if (*deadp) break;
        if (++spins > SPIN_MAX){ *deadp = 1; break; }
        __builtin_amdgcn_s_sleep(1);
      }
      vpack[par][tid]       = (uint32_t)v0;
      vpack[par][tid + 512] = (uint32_t)v1;
    } else {
      const u64* src = rhbuf + ((size_t)(rep*2 + par))*HP;
      const u64* zs  = zbufg + (size_t)par*2048 + 32*g;
      const bool needz = (tid < 32);
      u64 v0, v1, vz = 0; int spins = 0;
      const uint32_t want = (uint32_t)(t + 1);
      for(;;){
        v0 = aload(src + tid);
        v1 = aload(src + tid + 512);
        if (needz) vz = aload(zs + tid);
        bool ok = (uint32_t)(v0 >> 32) >= want &&
                  (uint32_t)(v1 >> 32) >= want &&
                  (!needz || (uint32_t)(vz >> 32) >= want);
        if (ok) break;
        if (*deadp) break;
        if (++spins > SPIN_MAX){ *deadp = 1; break; }
        __builtin_amdgcn_s_sleep(1);
      }
      vpack[par][tid]       = (uint32_t)v0;
      vpack[par][tid + 512] = (uint32_t)v1;
      if (needz) zsl[par][tid] = __uint_as_float((uint32_t)vz);
    }
    __syncthreads();
    if (*deadp) break;

    // ---- matvec: 16 MFMAs per wave, B-frag = broadcast vector slice ----
    {
      const uint32_t* vp = &vpack[par][wid*128];   // this wave's 256-elem k-slice
      const int boff = (lane >> 4) << 2;           // u32 idx of lane's 8 bf16
      f32x4 acc0 = {0.f,0.f,0.f,0.f}, acc1 = {0.f,0.f,0.f,0.f};
      #pragma unroll
      for (int s = 0; s < 8; ++s){
        uint4 bu = *(const uint4*)(vp + s*16 + boff);
        bf16x8 bf = __builtin_bit_cast(bf16x8, bu);
        acc0 = __builtin_amdgcn_mfma_f32_16x16x32_bf16(aw0[s], bf, acc0, 0, 0, 0);
        acc1 = __builtin_amdgcn_mfma_f32_16x16x32_bf16(aw1[s], bf, acc1, 0, 0, 0);
      }
      if ((lane & 15) == 0){                       // D[:,0]: m = (lane>>4)*4 + r
        int mb = (lane >> 4) << 2;
        #pragma unroll
        for (int r = 0; r < 4; ++r){
          red[(mb + r)*9 + wid]        = acc0[r];
          red[(16 + mb + r)*9 + wid]   = acc1[r];
        }
      }
    }
    __syncthreads();

    // ---- finalize: threads 0..31 own the block's 32 columns ----
    if (tid < 32){
      float acc = 0.f;
      #pragma unroll
      for (int w = 0; w < 8; ++w) acc += red[tid*9 + w];
      float pre = acc + gx[par][tid];

      if (isA){
        if (tid < 16){                             // r -> publish rh (bf16 pair) x NREP
          float r = 1.f / (1.f + __expf(-pre));
          int hcol = 16*g + tid;
          uint32_t hp = vpack[par][hcol >> 1];
          float hval = __uint_as_float((hcol & 1) ? (hp & 0xffff0000u) : (hp << 16));
          float rh = r * hval;
          float other = __shfl_xor(rh, 1);
          if (!(tid & 1)){
            u64 pv = ((u64)(uint32_t)(t + 1) << 32)
                   | ((u64)f2bf(other) << 16) | (u64)f2bf(rh);
            size_t idx = (size_t)((16*g + tid) >> 1);
            #pragma unroll
            for (int rp = 0; rp < NREP; ++rp)
              astore(rhbuf + (size_t)(rp*2 + par)*HP + idx, pv);
          }
        } else {                                   // z -> publish f32 (single copy)
          float z = 1.f / (1.f + __expf(-pre));
          u64 pv = ((u64)(uint32_t)(t + 1) << 32) | (u64)__float_as_uint(z);
          astore(zbufg + (size_t)par*2048 + 16*g + (tid - 16), pv);
        }
      } else {                                     // a -> h update -> publish h x NREP
        float e = __expf(2.f*pre);
        float a = 1.f - 2.f/(1.f + e);             // tanh, saturation-safe
        float z = zsl[par][tid];
        float hold = hloc[par][tid];
        float hnew = hold + z*(a - hold);          // (1-z)h + z*a
        float other = __shfl_xor(hnew, 1);
        if (!(tid & 1)){
          u64 pv = ((u64)(uint32_t)(t + 1) << 32)
                 | ((u64)f2bf(other) << 16) | (u64)f2bf(hnew);
          size_t idx = (size_t)((32*g + tid) >> 1);
          #pragma unroll
          for (int rp = 0; rp < NREP; ++rp)
            astore(hbuf + (size_t)(rp*2 + ((t+1)&1))*HP + idx, pv);
        }
        hloc[par ^ 1][tid] = hnew;
      }

      // gates prefetch for t+1: AFTER publish, so its HBM latency (and its
      // slot in the vmcnt queue) hides under the next fabric wait.
      if (gcol >= 0){
        int tn = (t + 1 < T_STEPS) ? t + 1 : t;
        gx[par ^ 1][tid] = gates[(size_t)tn*G3 + gcol] + bias;
      }
    }
  }

  // T even -> final h in hloc[0]; kernel-boundary flush makes it visible
  if (!isA && tid < 32) hfinal[32*g + tid] = hloc[0][tid];
}

// ---------------- out = h_final @ w_out + b_out ----------------------------
__global__ __launch_bounds__(1024) void out_proj(const float* __restrict__ hfin,
                                                 const float* __restrict__ w_out,
                                                 const float* __restrict__ b_out,
                                                 float* __restrict__ out){
  __shared__ float red[16][80];
  const int g  = blockIdx.x;
  const int cl = threadIdx.x & 63;
  const int kc = threadIdx.x >> 6;        // 0..15
  const int col = 64*g + cl;
  float acc = 0.f;
  for (int k = kc*128; k < kc*128 + 128; ++k)
    acc = fmaf(hfin[k], w_out[(size_t)k*EOUT + col], acc);
  red[kc][cl] = acc;
  __syncthreads();
  if (kc == 0){
    float s = 0.f;
    #pragma unroll
    for (int q = 0; q < 16; ++q) s += red[q][cl];
    out[col] = s + b_out[col];
  }
}

extern "C" void kernel_launch(void* const* d_in, const int* in_sizes, int n_in,
                              void* d_out, int out_size, void* d_ws, size_t ws_size,
                              hipStream_t stream) {
  const float* x     = (const float*)d_in[0];   // (8192, 2048)
  const float* w_i   = (const float*)d_in[1];   // (2048, 6144)
  const float* w_h   = (const float*)d_in[2];   // (2048, 6144)
  const float* b     = (const float*)d_in[3];   // (6144,)
  const float* w_out = (const float*)d_in[4];   // (2048, 512)
  const float* b_out = (const float*)d_in[5];   // (512,)
  float* out = (float*)d_out;

  // Workspace: gates f32 (201.3MB) | hbuf u64[8][2][1024] | rhbuf u64[8][2][1024]
  //            | zbufg u64[2][2048] | hfinal f32[2048]
  float* gates  = (float*)d_ws;
  u64*   hbuf   = (u64*)(gates + (size_t)T_STEPS * G3);
  u64*   rhbuf  = hbuf + (size_t)NREP*2*HP;
  u64*   zbufg  = rhbuf + (size_t)NREP*2*HP;
  float* hfinal = (float*)(zbufg + 2*2048);
  (void)in_sizes; (void)n_in; (void)out_size; (void)ws_size;

  // zero tagged buffers: h_0=0 tag0 ready; rh/z never ready until written
  hipMemsetAsync(hbuf, 0,
                 (size_t)(NREP*2*HP + NREP*2*HP + 2*2048)*sizeof(u64), stream);

  gates_gemm<<<dim3((T_STEPS/128)*(G3/128)), dim3(256), 0, stream>>>(x, w_i, gates);

  const float* gates_c = gates;
  void* kargs[7];
  kargs[0] = (void*)&gates_c;
  kargs[1] = (void*)&w_h;
  kargs[2] = (void*)&b;
  kargs[3] = (void*)&hbuf;
  kargs[4] = (void*)&rhbuf;
  kargs[5] = (void*)&zbufg;
  kargs[6] = (void*)&hfinal;
  hipLaunchCooperativeKernel((void*)scan_kernel, dim3(NA + NB), dim3(512), kargs, 0u, stream);

  out_proj<<<dim3(EOUT/64), dim3(1024), 0, stream>>>(hfinal, w_out, b_out, out);
}

// Round 7
// 31219.424 us; speedup vs baseline: 2.0778x; 1.0353x over previous
//
#include <hip/hip_runtime.h>
#include <stdint.h>

// Problem dims
#define T_STEPS 8192
#define DIN     2048
#define HD      2048
#define G3      6144
#define EOUT    512

// Scan partition: 64 A-blocks own 32 r-cols; 64 B-blocks own 32 z-cols +
// 32 a-cols + the h-update (z computed locally on B, off the critical path).
#define NA 64
#define NB 64
#define HP 1024          // h/rh broadcast: 1024 u64 pairs {tag | bf16 hi | bf16 lo}
#define NREP 8           // broadcast replicas (cuts LLC same-line fan-out)
#define SPIN_MAX (1<<20)

typedef unsigned long long u64;
typedef __attribute__((ext_vector_type(8))) __bf16 bf16x8;
typedef __attribute__((ext_vector_type(8))) unsigned short u16x8;
typedef __attribute__((ext_vector_type(4))) float f32x4;

__device__ __forceinline__ uint16_t f2bf(float v){   // RNE f32->bf16
  uint32_t x = __float_as_uint(v);
  return (uint16_t)((x + 0x7fffu + ((x >> 16) & 1u)) >> 16);
}

__device__ __forceinline__ u64 aload(const u64* p){
  return __hip_atomic_load(p, __ATOMIC_RELAXED, __HIP_MEMORY_SCOPE_AGENT);
}
__device__ __forceinline__ void astore(u64* p, u64 v){
  __hip_atomic_store(p, v, __ATOMIC_RELAXED, __HIP_MEMORY_SCOPE_AGENT);
}

// Software-pipelined tagged poll: keep one load batch in flight while testing
// the previous batch -> retry period ~ LLC-latency/2 instead of a full
// dependent round trip. Values+tags are atomic per u64, so whichever round
// first shows both tags fresh carries valid payloads.
__device__ __forceinline__ void poll2(const u64* p0, const u64* p1, uint32_t want,
                                      u64& r0, u64& r1, volatile int* deadp){
  u64 a0 = aload(p0), a1 = aload(p1);
  int spins = 0;
  for(;;){
    u64 b0 = aload(p0), b1 = aload(p1);          // next round already in flight
    if ((uint32_t)(a0 >> 32) >= want && (uint32_t)(a1 >> 32) >= want) break;
    if ((++spins & 63) == 0){
      if (*deadp) break;
      if (spins > SPIN_MAX){ *deadp = 1; break; }
    }
    a0 = b0; a1 = b1;
  }
  r0 = a0; r1 = a1;
}

// A-fragment loader: lane supplies A[m = lane&15][k = kb + j], j=0..7,
// from w_h column `col` (f32, row-major, stride G3), converted to bf16.
__device__ __forceinline__ bf16x8 load_afrag(const float* __restrict__ w, int col, int kb){
  u16x8 r;
  #pragma unroll
  for (int j = 0; j < 8; ++j)
    r[j] = f2bf(w[(size_t)(kb + j)*G3 + col]);
  return __builtin_bit_cast(bf16x8, r);
}

// One matvec pass: 16 MFMAs over this wave's 256-elem k-slice of the packed
// vector; two 16-column chains (wA, wB). Partials -> red[(col)*9 + wid].
__device__ __forceinline__ void mv_pass(const uint32_t* vp_base,
                                        const bf16x8* wA, const bf16x8* wB,
                                        float* red, int wid, int lane){
  const uint32_t* vp = vp_base + wid*128;
  const int boff = (lane >> 4) << 2;
  f32x4 acc0 = {0.f,0.f,0.f,0.f}, acc1 = {0.f,0.f,0.f,0.f};
  #pragma unroll
  for (int s = 0; s < 8; ++s){
    uint4 bu = *(const uint4*)(vp + s*16 + boff);
    bf16x8 bf = __builtin_bit_cast(bf16x8, bu);
    acc0 = __builtin_amdgcn_mfma_f32_16x16x32_bf16(wA[s], bf, acc0, 0, 0, 0);
    acc1 = __builtin_amdgcn_mfma_f32_16x16x32_bf16(wB[s], bf, acc1, 0, 0, 0);
  }
  if ((lane & 15) == 0){                         // D[:,0]: m = (lane>>4)*4 + r
    int mb = (lane >> 4) << 2;
    #pragma unroll
    for (int r = 0; r < 4; ++r){
      red[(mb + r)*9 + wid]      = acc0[r];
      red[(16 + mb + r)*9 + wid] = acc1[r];
    }
  }
}

// ------- gates GEMM (MFMA bf16): C[T,6144] = X[T,2048] @ Wi[2048,6144] -----
// 128x128 tile, BK=32, 8 waves (2x4). LDS pitch 40 bf16 (80B) keeps frag
// reads at 2-way bank aliasing (free) and 16B-aligned.
__global__ __launch_bounds__(512) void gates_gemm(const float* __restrict__ A,
                                                  const float* __restrict__ B,
                                                  float* __restrict__ C){
  __shared__ uint16_t Asb[128*40];
  __shared__ uint16_t Bsb[128*40];
  const int bm = blockIdx.x / (G3/128);
  const int bn = blockIdx.x % (G3/128);
  const int row0 = bm*128, col0 = bn*128;
  const int tid  = threadIdx.x;
  const int lane = tid & 63, wid = tid >> 6;
  const int wr = wid >> 2, wc = wid & 3;         // wave grid 2x4
  f32x4 acc[4][2] = {};
  for (int k0 = 0; k0 < DIN; k0 += 32){
    {   // stage A: [m][k] bf16, thread: m = tid>>2, ks = (tid&3)*8
      int m = tid >> 2, ks = (tid & 3) * 8;
      const float* src = A + (size_t)(row0 + m)*DIN + k0 + ks;
      float4 f0 = *(const float4*)src;
      float4 f1 = *(const float4*)(src + 4);
      u16x8 pk;
      pk[0]=f2bf(f0.x); pk[1]=f2bf(f0.y); pk[2]=f2bf(f0.z); pk[3]=f2bf(f0.w);
      pk[4]=f2bf(f1.x); pk[5]=f2bf(f1.y); pk[6]=f2bf(f1.z); pk[7]=f2bf(f1.w);
      *(u16x8*)(Asb + m*40 + ks) = pk;
    }
    {   // stage B transposed: [n][k] bf16, thread: k = tid>>4, n = (tid&15)+16i
      int k = tid >> 4, n8 = tid & 15;
      const float* src = B + (size_t)(k0 + k)*G3 + col0 + n8;
      #pragma unroll
      for (int i = 0; i < 8; ++i)
        Bsb[(n8 + 16*i)*40 + k] = f2bf(src[16*i]);
    }
    __syncthreads();
    const int mrow = wr*64, ncol = wc*32;
    const int fm = lane & 15, fk = (lane >> 4) * 8;
    bf16x8 bfr[2];
    #pragma unroll
    for (int j = 0; j < 2; ++j)
      bfr[j] = *(const bf16x8*)(Bsb + (ncol + j*16 + fm)*40 + fk);
    #pragma unroll
    for (int i = 0; i < 4; ++i){
      bf16x8 af = *(const bf16x8*)(Asb + (mrow + i*16 + fm)*40 + fk);
      acc[i][0] = __builtin_amdgcn_mfma_f32_16x16x32_bf16(af, bfr[0], acc[i][0], 0,0,0);
      acc[i][1] = __builtin_amdgcn_mfma_f32_16x16x32_bf16(af, bfr[1], acc[i][1], 0,0,0);
    }
    __syncthreads();
  }
  const int mrow = row0 + wr*64, ncol = col0 + wc*32;
  #pragma unroll
  for (int i = 0; i < 4; ++i)
    #pragma unroll
    for (int j = 0; j < 2; ++j){
      int cc = ncol + j*16 + (lane & 15);
      int rr = mrow + i*16 + (lane >> 4)*4;
      #pragma unroll
      for (int q = 0; q < 4; ++q)
        C[(size_t)(rr + q)*G3 + cc] = acc[i][j][q];
    }
}

// ---------------- persistent GRU scan --------------------------------------
// h_t:  hbuf [rep][t&1][1024]  {tag t   | 2x bf16}   (memset0 == h_0=0, tag 0)
// rh_t: rhbuf[rep][t&1][1024]  {tag t+1 | 2x bf16}
// A-block g: r-cols 2048+32g.. -> publishes rh slice.
// B-block g: z-cols 32g.. (computed at hop 1, overlapped with A's r-compute),
//            a-cols 4096+32g.., h-update for dims 32g.. -> publishes h slice.
__global__ __launch_bounds__(512) void scan_kernel(
    const float* __restrict__ gates, const float* __restrict__ w_h,
    const float* __restrict__ b,
    u64* hbuf, u64* rhbuf, float* hfinal)
{
  __shared__ uint32_t vph[2][1024];    // packed h pairs
  __shared__ uint32_t vprh[2][1024];   // packed rh pairs (B only)
  __shared__ float    red0[32*9];      // A: r partials. B: z partials
  __shared__ float    red1[32*9];      // B: a partials
  __shared__ float    gx[2][64];       // x-gates (+bias): A uses 32, B 64
  __shared__ float    hloc[2][32];     // local f32 h state (B)
  __shared__ int      dead;
  volatile int* deadp = &dead;

  const int tid  = threadIdx.x;
  const int lane = tid & 63;
  const int wid  = tid >> 6;
  const bool isA = blockIdx.x < NA;
  const int  g   = isA ? (int)blockIdx.x : (int)blockIdx.x - NA;
  const int  rep = blockIdx.x & (NREP - 1);

  // Persistent weight fragments, k = wid*256 + s*32 + (lane>>4)*8 + j
  bf16x8 w0[8], w1[8], w2[8], w3[8];
  {
    const int kb0 = wid*256 + ((lane >> 4) << 3);
    const int c0  = isA ? (2048 + 32*g) : (32*g);     // A: r. B: z
    #pragma unroll
    for (int s = 0; s < 8; ++s){
      w0[s] = load_afrag(w_h, c0 + (lane & 15),      kb0 + s*32);
      w1[s] = load_afrag(w_h, c0 + 16 + (lane & 15), kb0 + s*32);
    }
    if (!isA){
      const int ca = 4096 + 32*g;
      #pragma unroll
      for (int s = 0; s < 8; ++s){
        w2[s] = load_afrag(w_h, ca + (lane & 15),      kb0 + s*32);
        w3[s] = load_afrag(w_h, ca + 16 + (lane & 15), kb0 + s*32);
      }
    }
  }

  if (tid == 0) *deadp = 0;
  if (tid < 64) ((float*)hloc)[tid] = 0.f;

  int   gcol = -1;
  float bias = 0.f;
  if (isA) { if (tid < 32) gcol = 2048 + 32*g + tid; }            // r gates
  else     { if (tid < 32)      gcol = 32*g + tid;                // z gates
             else if (tid < 64) gcol = 4096 + 32*g + (tid - 32);} // a gates
  if (gcol >= 0) { bias = b[gcol]; gx[0][tid] = gates[gcol] + bias; }
  __syncthreads();

  for (int t = 0; t < T_STEPS; ++t){
    const int par = t & 1;

    // ---- hop 1: poll h_t (tag >= t), deposit packed pairs ----
    {
      const u64* src = hbuf + ((size_t)(rep*2 + par))*HP;
      u64 v0, v1;
      poll2(src + tid, src + tid + 512, (uint32_t)t, v0, v1, deadp);
      vph[par][tid]       = (uint32_t)v0;
      vph[par][tid + 512] = (uint32_t)v1;
    }
    __syncthreads();
    if (*deadp) break;

    if (isA){
      mv_pass(&vph[par][0], w0, w1, red0, wid, lane);   // r pre-activations
      __syncthreads();
      if (tid < 32){
        float acc = 0.f;
        #pragma unroll
        for (int w = 0; w < 8; ++w) acc += red0[tid*9 + w];
        float pre = acc + gx[par][tid];
        float r = 1.f / (1.f + __expf(-pre));
        int col = 32*g + tid;
        uint32_t hp = vph[par][col >> 1];
        float hval = __uint_as_float((col & 1) ? (hp & 0xffff0000u) : (hp << 16));
        float rh = r * hval;
        float other = __shfl_xor(rh, 1);
        if (!(tid & 1)){
          u64 pv = ((u64)(uint32_t)(t + 1) << 32)
                 | ((u64)f2bf(other) << 16) | (u64)f2bf(rh);
          size_t idx = (size_t)(col >> 1);
          #pragma unroll
          for (int rp = 0; rp < NREP; ++rp)
            astore(rhbuf + (size_t)(rp*2 + par)*HP + idx, pv);
        }
        // gates prefetch after publish: HBM latency hides under next poll
        int tn = (t + 1 < T_STEPS) ? t + 1 : t;
        gx[par ^ 1][tid] = gates[(size_t)tn*G3 + gcol] + bias;
      }
    } else {
      // z (off critical path; overlaps A's r-compute)
      mv_pass(&vph[par][0], w0, w1, red0, wid, lane);
      // ---- hop 2: poll rh_t (tag >= t+1), deposit ----
      {
        const u64* src = rhbuf + ((size_t)(rep*2 + par))*HP;
        u64 v0, v1;
        poll2(src + tid, src + tid + 512, (uint32_t)(t + 1), v0, v1, deadp);
        vprh[par][tid]       = (uint32_t)v0;
        vprh[par][tid + 512] = (uint32_t)v1;
      }
      __syncthreads();     // covers red0 writes + vprh deposits
      if (*deadp) break;
      mv_pass(&vprh[par][0], w2, w3, red1, wid, lane);  // a pre-activations
      __syncthreads();
      if (tid < 32){
        float zacc = 0.f, aacc = 0.f;
        #pragma unroll
        for (int w = 0; w < 8; ++w){ zacc += red0[tid*9 + w]; aacc += red1[tid*9 + w]; }
        float z = 1.f / (1.f + __expf(-(zacc + gx[par][tid])));
        float apre = aacc + gx[par][32 + tid];
        float e = __expf(2.f*apre);
        float a = 1.f - 2.f/(1.f + e);                  // tanh, saturation-safe
        float hold = hloc[par][tid];
        float hnew = hold + z*(a - hold);               // (1-z)h + z*a
        hloc[par ^ 1][tid] = hnew;
        float other = __shfl_xor(hnew, 1);
        if (!(tid & 1)){
          u64 pv = ((u64)(uint32_t)(t + 1) << 32)
                 | ((u64)f2bf(other) << 16) | (u64)f2bf(hnew);
          size_t idx = (size_t)((32*g + tid) >> 1);
          #pragma unroll
          for (int rp = 0; rp < NREP; ++rp)
            astore(hbuf + (size_t)(rp*2 + ((t+1)&1))*HP + idx, pv);
        }
      }
      if (gcol >= 0){      // prefetch both z and a gate columns (tid<64)
        int tn = (t + 1 < T_STEPS) ? t + 1 : t;
        gx[par ^ 1][tid] = gates[(size_t)tn*G3 + gcol] + bias;
      }
    }
  }

  // T even -> final h in hloc[0]; kernel-boundary flush makes it visible
  if (!isA && tid < 32) hfinal[32*g + tid] = hloc[0][tid];
}

// ---------------- out = h_final @ w_out + b_out ----------------------------
__global__ __launch_bounds__(1024) void out_proj(const float* __restrict__ hfin,
                                                 const float* __restrict__ w_out,
                                                 const float* __restrict__ b_out,
                                                 float* __restrict__ out){
  __shared__ float red[16][80];
  const int g  = blockIdx.x;
  const int cl = threadIdx.x & 63;
  const int kc = threadIdx.x >> 6;        // 0..15
  const int col = 64*g + cl;
  float acc = 0.f;
  for (int k = kc*128; k < kc*128 + 128; ++k)
    acc = fmaf(hfin[k], w_out[(size_t)k*EOUT + col], acc);
  red[kc][cl] = acc;
  __syncthreads();
  if (kc == 0){
    float s = 0.f;
    #pragma unroll
    for (int q = 0; q < 16; ++q) s += red[q][cl];
    out[col] = s + b_out[col];
  }
}

extern "C" void kernel_launch(void* const* d_in, const int* in_sizes, int n_in,
                              void* d_out, int out_size, void* d_ws, size_t ws_size,
                              hipStream_t stream) {
  const float* x     = (const float*)d_in[0];   // (8192, 2048)
  const float* w_i   = (const float*)d_in[1];   // (2048, 6144)
  const float* w_h   = (const float*)d_in[2];   // (2048, 6144)
  const float* b     = (const float*)d_in[3];   // (6144,)
  const float* w_out = (const float*)d_in[4];   // (2048, 512)
  const float* b_out = (const float*)d_in[5];   // (512,)
  float* out = (float*)d_out;

  // Workspace: gates f32 (201.3MB) | hbuf u64[8][2][1024] | rhbuf u64[8][2][1024]
  //            | hfinal f32[2048]
  float* gates  = (float*)d_ws;
  u64*   hbuf   = (u64*)(gates + (size_t)T_STEPS * G3);
  u64*   rhbuf  = hbuf + (size_t)NREP*2*HP;
  float* hfinal = (float*)(rhbuf + (size_t)NREP*2*HP);
  (void)in_sizes; (void)n_in; (void)out_size; (void)ws_size;

  // zero tagged buffers: h_0=0 tag0 ready; rh never ready until written
  hipMemsetAsync(hbuf, 0, (size_t)(2*NREP*2*HP)*sizeof(u64), stream);

  gates_gemm<<<dim3((T_STEPS/128)*(G3/128)), dim3(512), 0, stream>>>(x, w_i, gates);

  const float* gates_c = gates;
  void* kargs[6];
  kargs[0] = (void*)&gates_c;
  kargs[1] = (void*)&w_h;
  kargs[2] = (void*)&b;
  kargs[3] = (void*)&hbuf;
  kargs[4] = (void*)&rhbuf;
  kargs[5] = (void*)&hfinal;
  hipLaunchCooperativeKernel((void*)scan_kernel, dim3(NA + NB), dim3(512), kargs, 0u, stream);

  out_proj<<<dim3(EOUT/64), dim3(1024), 0, stream>>>(hfinal, w_out, b_out, out);
}

// Round 8
// 27665.231 us; speedup vs baseline: 2.3447x; 1.1285x over previous
//
#include <hip/hip_runtime.h>
#include <stdint.h>

// Problem dims
#define T_STEPS 8192
#define DIN     2048
#define HD      2048
#define G3      6144
#define EOUT    512

// Scan partition: 64 A-blocks own 32 r-cols; 64 B-blocks own 32 z-cols +
// 32 a-cols + the h-update (z computed locally on B, off the critical path).
#define NA 64
#define NB 64
#define HP 1024          // h/rh broadcast: 1024 u64 pairs {tag | bf16 hi | bf16 lo}
#define NREP 8           // broadcast replicas
#define SPIN_MAX (1<<20)

typedef unsigned long long u64;
typedef __attribute__((ext_vector_type(8))) __bf16 bf16x8;
typedef __attribute__((ext_vector_type(8))) unsigned short u16x8;
typedef __attribute__((ext_vector_type(4))) float f32x4;

__device__ __forceinline__ uint16_t f2bf(float v){   // RNE f32->bf16
  uint32_t x = __float_as_uint(v);
  return (uint16_t)((x + 0x7fffu + ((x >> 16) & 1u)) >> 16);
}

__device__ __forceinline__ u64 aload(const u64* p){
  return __hip_atomic_load(p, __ATOMIC_RELAXED, __HIP_MEMORY_SCOPE_AGENT);
}
__device__ __forceinline__ void astore(u64* p, u64 v){
  __hip_atomic_store(p, v, __ATOMIC_RELAXED, __HIP_MEMORY_SCOPE_AGENT);
}

// A-fragment loader: lane supplies A[m = lane&15][k = kb + j], j=0..7,
// from w_h column `col` (f32, row-major, stride G3), converted to bf16.
__device__ __forceinline__ bf16x8 load_afrag(const float* __restrict__ w, int col, int kb){
  u16x8 r;
  #pragma unroll
  for (int j = 0; j < 8; ++j)
    r[j] = f2bf(w[(size_t)(kb + j)*G3 + col]);
  return __builtin_bit_cast(bf16x8, r);
}

// Wave-local tagged slice poll + LDS deposit. Each wave owns u64 elements
// [wid*128, wid*128+128) of the broadcast vector: lane takes the adjacent
// pair (2*lane, 2*lane+1) -> after tags are fresh, packs the two u32
// payloads into one ds_write_b64. If OWN=true, lanes 0..15 additionally
// poll u64 element (own_base + lane) and return it (A-finalize h values).
template<bool OWN>
__device__ __forceinline__ u64 poll_slice(const u64* src, uint32_t want,
                                          uint32_t* lds_slice, int own_base,
                                          int lane, volatile int* deadp){
  const u64* p0 = src + 2*lane;
  const u64* p1 = p0 + 1;
  const u64* po = src + own_base + lane;
  const bool need_own = OWN && (lane < 16);
  u64 v0, v1, vo = 0;
  int spins = 0;
  for(;;){
    v0 = aload(p0); v1 = aload(p1);
    if (need_own) vo = aload(po);
    bool ok = (uint32_t)(v0 >> 32) >= want && (uint32_t)(v1 >> 32) >= want &&
              (!need_own || (uint32_t)(vo >> 32) >= want);
    if (__all(ok)) break;
    if ((++spins & 63) == 0){
      if (*deadp) break;
      if (spins > SPIN_MAX){ *deadp = 1; break; }
    }
    __builtin_amdgcn_s_sleep(1);
  }
  u64 pk = ((u64)(uint32_t)v1 << 32) | (u64)(uint32_t)v0;
  *(u64*)&lds_slice[2*lane] = pk;         // wave-local; lgkmcnt orders vs reads
  return vo;
}

// One matvec pass over this wave's 256-elem k-slice: 16 MFMAs, two 16-col
// chains (wA, wB). Partials -> red[col*9 + wid]. Reads only the wave's own
// LDS slice (no cross-wave dependency -> no barrier needed before this).
__device__ __forceinline__ void mv_pass(const uint32_t* vp,
                                        const bf16x8* wA, const bf16x8* wB,
                                        float* red, int wid, int lane){
  const int boff = (lane >> 4) << 2;
  f32x4 acc0 = {0.f,0.f,0.f,0.f}, acc1 = {0.f,0.f,0.f,0.f};
  #pragma unroll
  for (int s = 0; s < 8; ++s){
    uint4 bu = *(const uint4*)(vp + s*16 + boff);
    bf16x8 bf = __builtin_bit_cast(bf16x8, bu);
    acc0 = __builtin_amdgcn_mfma_f32_16x16x32_bf16(wA[s], bf, acc0, 0, 0, 0);
    acc1 = __builtin_amdgcn_mfma_f32_16x16x32_bf16(wB[s], bf, acc1, 0, 0, 0);
  }
  if ((lane & 15) == 0){                  // D[:,0]: m = (lane>>4)*4 + r
    int mb = (lane >> 4) << 2;
    #pragma unroll
    for (int r = 0; r < 4; ++r){
      red[(mb + r)*9 + wid]      = acc0[r];
      red[(16 + mb + r)*9 + wid] = acc1[r];
    }
  }
}

// ------- gates GEMM (MFMA bf16): C[T,6144] = X[T,2048] @ Wi[2048,6144] -----
__global__ __launch_bounds__(512) void gates_gemm(const float* __restrict__ A,
                                                  const float* __restrict__ B,
                                                  float* __restrict__ C){
  __shared__ uint16_t Asb[128*40];
  __shared__ uint16_t Bsb[128*40];
  const int bm = blockIdx.x / (G3/128);
  const int bn = blockIdx.x % (G3/128);
  const int row0 = bm*128, col0 = bn*128;
  const int tid  = threadIdx.x;
  const int lane = tid & 63, wid = tid >> 6;
  const int wr = wid >> 2, wc = wid & 3;         // wave grid 2x4
  f32x4 acc[4][2] = {};
  for (int k0 = 0; k0 < DIN; k0 += 32){
    {   // stage A: [m][k] bf16
      int m = tid >> 2, ks = (tid & 3) * 8;
      const float* src = A + (size_t)(row0 + m)*DIN + k0 + ks;
      float4 f0 = *(const float4*)src;
      float4 f1 = *(const float4*)(src + 4);
      u16x8 pk;
      pk[0]=f2bf(f0.x); pk[1]=f2bf(f0.y); pk[2]=f2bf(f0.z); pk[3]=f2bf(f0.w);
      pk[4]=f2bf(f1.x); pk[5]=f2bf(f1.y); pk[6]=f2bf(f1.z); pk[7]=f2bf(f1.w);
      *(u16x8*)(Asb + m*40 + ks) = pk;
    }
    {   // stage B transposed: [n][k] bf16
      int k = tid >> 4, n8 = tid & 15;
      const float* src = B + (size_t)(k0 + k)*G3 + col0 + n8;
      #pragma unroll
      for (int i = 0; i < 8; ++i)
        Bsb[(n8 + 16*i)*40 + k] = f2bf(src[16*i]);
    }
    __syncthreads();
    const int mrow = wr*64, ncol = wc*32;
    const int fm = lane & 15, fk = (lane >> 4) * 8;
    bf16x8 bfr[2];
    #pragma unroll
    for (int j = 0; j < 2; ++j)
      bfr[j] = *(const bf16x8*)(Bsb + (ncol + j*16 + fm)*40 + fk);
    #pragma unroll
    for (int i = 0; i < 4; ++i){
      bf16x8 af = *(const bf16x8*)(Asb + (mrow + i*16 + fm)*40 + fk);
      acc[i][0] = __builtin_amdgcn_mfma_f32_16x16x32_bf16(af, bfr[0], acc[i][0], 0,0,0);
      acc[i][1] = __builtin_amdgcn_mfma_f32_16x16x32_bf16(af, bfr[1], acc[i][1], 0,0,0);
    }
    __syncthreads();
  }
  const int mrow = row0 + wr*64, ncol = col0 + wc*32;
  #pragma unroll
  for (int i = 0; i < 4; ++i)
    #pragma unroll
    for (int j = 0; j < 2; ++j){
      int cc = ncol + j*16 + (lane & 15);
      int rr = mrow + i*16 + (lane >> 4)*4;
      #pragma unroll
      for (int q = 0; q < 4; ++q)
        C[(size_t)(rr + q)*G3 + cc] = acc[i][j][q];
    }
}

// ---------------- persistent GRU scan --------------------------------------
// h_t:  hbuf [rep][t&1][1024]  {tag t   | 2x bf16}   (memset0 == h_0=0, tag 0)
// rh_t: rhbuf[rep][t&1][1024]  {tag t+1 | 2x bf16}
// Intra-block: wave-local slice poll -> deposit -> MFMA with NO barrier;
// exactly ONE __syncthreads per step (before the wave-0 finalize).
__global__ __launch_bounds__(512) void scan_kernel(
    const float* __restrict__ gates, const float* __restrict__ w_h,
    const float* __restrict__ b,
    u64* hbuf, u64* rhbuf, float* hfinal)
{
  __shared__ uint32_t vph[2][1024];    // packed h pairs
  __shared__ uint32_t vprh[2][1024];   // packed rh pairs (B only)
  __shared__ float    red0[32*9];      // A: r partials. B: z partials
  __shared__ float    red1[32*9];      // B: a partials
  __shared__ float    gx[2][64];       // x-gates (+bias): A uses 32, B 64
  __shared__ float    hloc[2][32];     // local f32 h state (B)
  __shared__ int      dead;
  volatile int* deadp = &dead;

  const int tid  = threadIdx.x;
  const int lane = tid & 63;
  const int wid  = tid >> 6;
  const bool isA = blockIdx.x < NA;
  const int  g   = isA ? (int)blockIdx.x : (int)blockIdx.x - NA;
  const int  rep = blockIdx.x & (NREP - 1);

  // Persistent weight fragments, k = wid*256 + s*32 + (lane>>4)*8 + j
  bf16x8 w0[8], w1[8], w2[8], w3[8];
  {
    const int kb0 = wid*256 + ((lane >> 4) << 3);
    const int c0  = isA ? (2048 + 32*g) : (32*g);     // A: r. B: z
    #pragma unroll
    for (int s = 0; s < 8; ++s){
      w0[s] = load_afrag(w_h, c0 + (lane & 15),      kb0 + s*32);
      w1[s] = load_afrag(w_h, c0 + 16 + (lane & 15), kb0 + s*32);
    }
    if (!isA){
      const int ca = 4096 + 32*g;
      #pragma unroll
      for (int s = 0; s < 8; ++s){
        w2[s] = load_afrag(w_h, ca + (lane & 15),      kb0 + s*32);
        w3[s] = load_afrag(w_h, ca + 16 + (lane & 15), kb0 + s*32);
      }
    }
  }

  if (tid == 0) *deadp = 0;
  if (tid < 64) ((float*)hloc)[tid] = 0.f;

  int   gcol = -1;
  float bias = 0.f;
  if (isA) { if (tid < 32) gcol = 2048 + 32*g + tid; }            // r gates
  else     { if (tid < 32)      gcol = 32*g + tid;                // z gates
             else if (tid < 64) gcol = 4096 + 32*g + (tid - 32);} // a gates
  if (gcol >= 0) { bias = b[gcol]; gx[0][tid] = gates[gcol] + bias; }
  __syncthreads();

  for (int t = 0; t < T_STEPS; ++t){
    const int par = t & 1;

    if (isA){
      // hop 1: wave-local h-slice poll+deposit; wave 0 also grabs own 16 h u64s
      const u64* src = hbuf + ((size_t)(rep*2 + par))*HP;
      u64 vo;
      if (wid == 0)
        vo = poll_slice<true >(src, (uint32_t)t, &vph[par][0],       16*g, lane, deadp);
      else
        vo = poll_slice<false>(src + wid*128, (uint32_t)t,
                               &vph[par][wid*128], 0, lane, deadp);
      mv_pass(&vph[par][wid*128], w0, w1, red0, wid, lane);  // r pre-activations
      __syncthreads();
      if (*deadp) break;
      if (wid == 0){
        // h values for rh: lane tid<32 needs payload of own-u64 (tid>>1), half (tid&1)
        uint32_t hp = __shfl((int)(uint32_t)vo, lane >> 1);
        if (lane < 32){
          float acc = 0.f;
          #pragma unroll
          for (int w = 0; w < 8; ++w) acc += red0[lane*9 + w];
          float pre = acc + gx[par][lane];
          float r = 1.f / (1.f + __expf(-pre));
          float hval = __uint_as_float((lane & 1) ? (hp & 0xffff0000u) : (hp << 16));
          float rh = r * hval;
          float other = __shfl_xor(rh, 1);
          if (!(lane & 1)){
            u64 pv = ((u64)(uint32_t)(t + 1) << 32)
                   | ((u64)f2bf(other) << 16) | (u64)f2bf(rh);
            size_t idx = (size_t)((32*g + lane) >> 1);
            #pragma unroll
            for (int rp = 0; rp < NREP; ++rp)
              astore(rhbuf + (size_t)(rp*2 + par)*HP + idx, pv);
          }
          // gates prefetch after publish: HBM latency hides under next poll
          int tn = (t + 1 < T_STEPS) ? t + 1 : t;
          gx[par ^ 1][lane] = gates[(size_t)tn*G3 + gcol] + bias;
        }
      }
    } else {
      // hop 1: h slice (for z); z-mv overlaps A's r-compute
      const u64* hsrc = hbuf + ((size_t)(rep*2 + par))*HP;
      poll_slice<false>(hsrc + wid*128, (uint32_t)t, &vph[par][wid*128], 0, lane, deadp);
      mv_pass(&vph[par][wid*128], w0, w1, red0, wid, lane);  // z partials
      // hop 2: rh slice
      const u64* rsrc = rhbuf + ((size_t)(rep*2 + par))*HP;
      poll_slice<false>(rsrc + wid*128, (uint32_t)(t + 1), &vprh[par][wid*128], 0, lane, deadp);
      mv_pass(&vprh[par][wid*128], w2, w3, red1, wid, lane); // a partials
      __syncthreads();
      if (*deadp) break;
      if (wid == 0 && lane < 32){
        float zacc = 0.f, aacc = 0.f;
        #pragma unroll
        for (int w = 0; w < 8; ++w){ zacc += red0[lane*9 + w]; aacc += red1[lane*9 + w]; }
        float z = 1.f / (1.f + __expf(-(zacc + gx[par][lane])));
        float apre = aacc + gx[par][32 + lane];
        float e = __expf(2.f*apre);
        float a = 1.f - 2.f/(1.f + e);                  // tanh, saturation-safe
        float hold = hloc[par][lane];
        float hnew = hold + z*(a - hold);               // (1-z)h + z*a
        hloc[par ^ 1][lane] = hnew;
        float other = __shfl_xor(hnew, 1);
        if (!(lane & 1)){
          u64 pv = ((u64)(uint32_t)(t + 1) << 32)
                 | ((u64)f2bf(other) << 16) | (u64)f2bf(hnew);
          size_t idx = (size_t)((32*g + lane) >> 1);
          #pragma unroll
          for (int rp = 0; rp < NREP; ++rp)
            astore(hbuf + (size_t)(rp*2 + ((t+1)&1))*HP + idx, pv);
        }
      }
      if (wid == 0 && gcol >= 0){        // prefetch z and a gate columns
        int tn = (t + 1 < T_STEPS) ? t + 1 : t;
        gx[par ^ 1][lane] = gates[(size_t)tn*G3 + gcol] + bias;
      }
    }
  }

  // T even -> final h in hloc[0]; kernel-boundary flush makes it visible
  if (!isA && tid < 32) hfinal[32*g + tid] = hloc[0][tid];
}

// ---------------- out = h_final @ w_out + b_out ----------------------------
__global__ __launch_bounds__(1024) void out_proj(const float* __restrict__ hfin,
                                                 const float* __restrict__ w_out,
                                                 const float* __restrict__ b_out,
                                                 float* __restrict__ out){
  __shared__ float red[16][80];
  const int g  = blockIdx.x;
  const int cl = threadIdx.x & 63;
  const int kc = threadIdx.x >> 6;        // 0..15
  const int col = 64*g + cl;
  float acc = 0.f;
  for (int k = kc*128; k < kc*128 + 128; ++k)
    acc = fmaf(hfin[k], w_out[(size_t)k*EOUT + col], acc);
  red[kc][cl] = acc;
  __syncthreads();
  if (kc == 0){
    float s = 0.f;
    #pragma unroll
    for (int q = 0; q < 16; ++q) s += red[q][cl];
    out[col] = s + b_out[col];
  }
}

extern "C" void kernel_launch(void* const* d_in, const int* in_sizes, int n_in,
                              void* d_out, int out_size, void* d_ws, size_t ws_size,
                              hipStream_t stream) {
  const float* x     = (const float*)d_in[0];   // (8192, 2048)
  const float* w_i   = (const float*)d_in[1];   // (2048, 6144)
  const float* w_h   = (const float*)d_in[2];   // (2048, 6144)
  const float* b     = (const float*)d_in[3];   // (6144,)
  const float* w_out = (const float*)d_in[4];   // (2048, 512)
  const float* b_out = (const float*)d_in[5];   // (512,)
  float* out = (float*)d_out;

  // Workspace: gates f32 (201.3MB) | hbuf u64[8][2][1024] | rhbuf u64[8][2][1024]
  //            | hfinal f32[2048]
  float* gates  = (float*)d_ws;
  u64*   hbuf   = (u64*)(gates + (size_t)T_STEPS * G3);
  u64*   rhbuf  = hbuf + (size_t)NREP*2*HP;
  float* hfinal = (float*)(rhbuf + (size_t)NREP*2*HP);
  (void)in_sizes; (void)n_in; (void)out_size; (void)ws_size;

  // zero tagged buffers: h_0=0 tag0 ready; rh never ready until written
  hipMemsetAsync(hbuf, 0, (size_t)(2*NREP*2*HP)*sizeof(u64), stream);

  gates_gemm<<<dim3((T_STEPS/128)*(G3/128)), dim3(512), 0, stream>>>(x, w_i, gates);

  const float* gates_c = gates;
  void* kargs[6];
  kargs[0] = (void*)&gates_c;
  kargs[1] = (void*)&w_h;
  kargs[2] = (void*)&b;
  kargs[3] = (void*)&hbuf;
  kargs[4] = (void*)&rhbuf;
  kargs[5] = (void*)&hfinal;
  hipLaunchCooperativeKernel((void*)scan_kernel, dim3(NA + NB), dim3(512), kargs, 0u, stream);

  out_proj<<<dim3(EOUT/64), dim3(1024), 0, stream>>>(hfinal, w_out, b_out, out);
}

// Round 9
// 27621.585 us; speedup vs baseline: 2.3484x; 1.0016x over previous
//
#include <hip/hip_runtime.h>
#include <stdint.h>

// Problem dims
#define T_STEPS 8192
#define DIN     2048
#define HD      2048
#define G3      6144
#define EOUT    512

// Scan partition: 64 A-blocks own 32 r-cols; 64 B-blocks own 32 z-cols +
// 32 a-cols + the h-update (z computed locally on B, off the critical path).
#define NA 64
#define NB 64
#define HP 1024          // h/rh broadcast: 1024 u64 pairs {tag | bf16 hi | bf16 lo}
#define NREP 8           // broadcast replicas
#define SPIN_MAX (1<<20)

typedef unsigned long long u64;
typedef __attribute__((ext_vector_type(8))) __bf16 bf16x8;
typedef __attribute__((ext_vector_type(8))) unsigned short u16x8;
typedef __attribute__((ext_vector_type(4))) float f32x4;

__device__ __forceinline__ uint16_t f2bf(float v){   // RNE f32->bf16
  uint32_t x = __float_as_uint(v);
  return (uint16_t)((x + 0x7fffu + ((x >> 16) & 1u)) >> 16);
}

__device__ __forceinline__ u64 aload(const u64* p){
  return __hip_atomic_load(p, __ATOMIC_RELAXED, __HIP_MEMORY_SCOPE_AGENT);
}
__device__ __forceinline__ void astore(u64* p, u64 v){
  __hip_atomic_store(p, v, __ATOMIC_RELAXED, __HIP_MEMORY_SCOPE_AGENT);
}

// A-fragment loader: lane supplies A[m = lane&15][k = kb + j], j=0..7,
// from w_h column `col` (f32, row-major, stride G3), converted to bf16.
__device__ __forceinline__ bf16x8 load_afrag(const float* __restrict__ w, int col, int kb){
  u16x8 r;
  #pragma unroll
  for (int j = 0; j < 8; ++j)
    r[j] = f2bf(w[(size_t)(kb + j)*G3 + col]);
  return __builtin_bit_cast(bf16x8, r);
}

// Wave-local tagged slice poll + LDS deposit. Each wave owns u64 elements
// [wid*128, wid*128+128) of the broadcast vector: lane takes the adjacent
// pair (2*lane, 2*lane+1) -> after tags are fresh, packs the two u32
// payloads into one ds_write_b64. If OWN=true, lanes 0..15 additionally
// poll u64 element (own_base + lane) and return it (A-finalize h values).
template<bool OWN>
__device__ __forceinline__ u64 poll_slice(const u64* src, uint32_t want,
                                          uint32_t* lds_slice, int own_base,
                                          int lane, volatile int* deadp){
  const u64* p0 = src + 2*lane;
  const u64* p1 = p0 + 1;
  const u64* po = src + own_base + lane;
  const bool need_own = OWN && (lane < 16);
  u64 v0, v1, vo = 0;
  int spins = 0;
  for(;;){
    v0 = aload(p0); v1 = aload(p1);
    if (need_own) vo = aload(po);
    bool ok = (uint32_t)(v0 >> 32) >= want && (uint32_t)(v1 >> 32) >= want &&
              (!need_own || (uint32_t)(vo >> 32) >= want);
    if (__all(ok)) break;
    if ((++spins & 63) == 0){
      if (*deadp) break;
      if (spins > SPIN_MAX){ *deadp = 1; break; }
    }
    __builtin_amdgcn_s_sleep(1);
  }
  u64 pk = ((u64)(uint32_t)v1 << 32) | (u64)(uint32_t)v0;
  *(u64*)&lds_slice[2*lane] = pk;         // wave-local; lgkmcnt orders vs reads
  return vo;
}

// One matvec pass over this wave's 256-elem k-slice: 16 MFMAs, two 16-col
// chains (wA, wB). Partials -> red[col*9 + wid]. Reads only the wave's own
// LDS slice (no cross-wave dependency -> no barrier needed before this).
__device__ __forceinline__ void mv_pass(const uint32_t* vp,
                                        const bf16x8* wA, const bf16x8* wB,
                                        float* red, int wid, int lane){
  const int boff = (lane >> 4) << 2;
  f32x4 acc0 = {0.f,0.f,0.f,0.f}, acc1 = {0.f,0.f,0.f,0.f};
  #pragma unroll
  for (int s = 0; s < 8; ++s){
    uint4 bu = *(const uint4*)(vp + s*16 + boff);
    bf16x8 bf = __builtin_bit_cast(bf16x8, bu);
    acc0 = __builtin_amdgcn_mfma_f32_16x16x32_bf16(wA[s], bf, acc0, 0, 0, 0);
    acc1 = __builtin_amdgcn_mfma_f32_16x16x32_bf16(wB[s], bf, acc1, 0, 0, 0);
  }
  if ((lane & 15) == 0){                  // D[:,0]: m = (lane>>4)*4 + r
    int mb = (lane >> 4) << 2;
    #pragma unroll
    for (int r = 0; r < 4; ++r){
      red[(mb + r)*9 + wid]      = acc0[r];
      red[(16 + mb + r)*9 + wid] = acc1[r];
    }
  }
}

// ------- gates GEMM (MFMA bf16): C[T,6144] = X[T,2048] @ Wi[2048,6144] -----
__global__ __launch_bounds__(512) void gates_gemm(const float* __restrict__ A,
                                                  const float* __restrict__ B,
                                                  float* __restrict__ C){
  __shared__ uint16_t Asb[128*40];
  __shared__ uint16_t Bsb[128*40];
  const int bm = blockIdx.x / (G3/128);
  const int bn = blockIdx.x % (G3/128);
  const int row0 = bm*128, col0 = bn*128;
  const int tid  = threadIdx.x;
  const int lane = tid & 63, wid = tid >> 6;
  const int wr = wid >> 2, wc = wid & 3;         // wave grid 2x4
  f32x4 acc[4][2] = {};
  for (int k0 = 0; k0 < DIN; k0 += 32){
    {   // stage A: [m][k] bf16
      int m = tid >> 2, ks = (tid & 3) * 8;
      const float* src = A + (size_t)(row0 + m)*DIN + k0 + ks;
      float4 f0 = *(const float4*)src;
      float4 f1 = *(const float4*)(src + 4);
      u16x8 pk;
      pk[0]=f2bf(f0.x); pk[1]=f2bf(f0.y); pk[2]=f2bf(f0.z); pk[3]=f2bf(f0.w);
      pk[4]=f2bf(f1.x); pk[5]=f2bf(f1.y); pk[6]=f2bf(f1.z); pk[7]=f2bf(f1.w);
      *(u16x8*)(Asb + m*40 + ks) = pk;
    }
    {   // stage B transposed: [n][k] bf16
      int k = tid >> 4, n8 = tid & 15;
      const float* src = B + (size_t)(k0 + k)*G3 + col0 + n8;
      #pragma unroll
      for (int i = 0; i < 8; ++i)
        Bsb[(n8 + 16*i)*40 + k] = f2bf(src[16*i]);
    }
    __syncthreads();
    const int mrow = wr*64, ncol = wc*32;
    const int fm = lane & 15, fk = (lane >> 4) * 8;
    bf16x8 bfr[2];
    #pragma unroll
    for (int j = 0; j < 2; ++j)
      bfr[j] = *(const bf16x8*)(Bsb + (ncol + j*16 + fm)*40 + fk);
    #pragma unroll
    for (int i = 0; i < 4; ++i){
      bf16x8 af = *(const bf16x8*)(Asb + (mrow + i*16 + fm)*40 + fk);
      acc[i][0] = __builtin_amdgcn_mfma_f32_16x16x32_bf16(af, bfr[0], acc[i][0], 0,0,0);
      acc[i][1] = __builtin_amdgcn_mfma_f32_16x16x32_bf16(af, bfr[1], acc[i][1], 0,0,0);
    }
    __syncthreads();
  }
  const int mrow = row0 + wr*64, ncol = col0 + wc*32;
  #pragma unroll
  for (int i = 0; i < 4; ++i)
    #pragma unroll
    for (int j = 0; j < 2; ++j){
      int cc = ncol + j*16 + (lane & 15);
      int rr = mrow + i*16 + (lane >> 4)*4;
      #pragma unroll
      for (int q = 0; q < 4; ++q)
        C[(size_t)(rr + q)*G3 + cc] = acc[i][j][q];
    }
}

// ---------------- persistent GRU scan --------------------------------------
// h_t:  hbuf [rep][t&1][1024]  {tag t   | 2x bf16}   (memset0 == h_0=0, tag 0)
// rh_t: rhbuf[rep][t&1][1024]  {tag t+1 | 2x bf16}
// Intra-block: wave-local slice poll -> deposit -> MFMA with NO barrier;
// exactly ONE __syncthreads per step (before the wave-0 finalize).
__global__ __launch_bounds__(512) void scan_kernel(
    const float* __restrict__ gates, const float* __restrict__ w_h,
    const float* __restrict__ b,
    u64* hbuf, u64* rhbuf, float* hfinal)
{
  __shared__ uint32_t vph[2][1024];    // packed h pairs
  __shared__ uint32_t vprh[2][1024];   // packed rh pairs (B only)
  __shared__ float    red0[32*9];      // A: r partials. B: z partials
  __shared__ float    red1[32*9];      // B: a partials
  __shared__ float    gx[2][64];       // x-gates (+bias): A uses 32, B 64
  __shared__ float    hloc[2][32];     // local f32 h state (B)
  __shared__ int      dead;
  volatile int* deadp = &dead;

  const int tid  = threadIdx.x;
  const int lane = tid & 63;
  const int wid  = tid >> 6;
  const bool isA = blockIdx.x < NA;
  const int  g   = isA ? (int)blockIdx.x : (int)blockIdx.x - NA;
  const int  rep = blockIdx.x & (NREP - 1);

  // Persistent weight fragments, k = wid*256 + s*32 + (lane>>4)*8 + j
  bf16x8 w0[8], w1[8], w2[8], w3[8];
  {
    const int kb0 = wid*256 + ((lane >> 4) << 3);
    const int c0  = isA ? (2048 + 32*g) : (32*g);     // A: r. B: z
    #pragma unroll
    for (int s = 0; s < 8; ++s){
      w0[s] = load_afrag(w_h, c0 + (lane & 15),      kb0 + s*32);
      w1[s] = load_afrag(w_h, c0 + 16 + (lane & 15), kb0 + s*32);
    }
    if (!isA){
      const int ca = 4096 + 32*g;
      #pragma unroll
      for (int s = 0; s < 8; ++s){
        w2[s] = load_afrag(w_h, ca + (lane & 15),      kb0 + s*32);
        w3[s] = load_afrag(w_h, ca + 16 + (lane & 15), kb0 + s*32);
      }
    }
  }

  if (tid == 0) *deadp = 0;
  if (tid < 64) ((float*)hloc)[tid] = 0.f;

  int   gcol = -1;
  float bias = 0.f;
  if (isA) { if (tid < 32) gcol = 2048 + 32*g + tid; }            // r gates
  else     { if (tid < 32)      gcol = 32*g + tid;                // z gates
             else if (tid < 64) gcol = 4096 + 32*g + (tid - 32);} // a gates
  if (gcol >= 0) { bias = b[gcol]; gx[0][tid] = gates[gcol] + bias; }
  __syncthreads();

  for (int t = 0; t < T_STEPS; ++t){
    const int par = t & 1;

    if (isA){
      // hop 1: wave-local h-slice poll+deposit; wave 0 also grabs own 16 h u64s
      const u64* src = hbuf + ((size_t)(rep*2 + par))*HP;
      u64 vo;
      if (wid == 0)
        vo = poll_slice<true >(src, (uint32_t)t, &vph[par][0],       16*g, lane, deadp);
      else
        vo = poll_slice<false>(src + wid*128, (uint32_t)t,
                               &vph[par][wid*128], 0, lane, deadp);
      mv_pass(&vph[par][wid*128], w0, w1, red0, wid, lane);  // r pre-activations
      __syncthreads();
      if (*deadp) break;
      if (wid == 0){
        // h values for rh: lane tid<32 needs payload of own-u64 (tid>>1), half (tid&1)
        uint32_t hp = __shfl((int)(uint32_t)vo, lane >> 1);
        if (lane < 32){
          float acc = 0.f;
          #pragma unroll
          for (int w = 0; w < 8; ++w) acc += red0[lane*9 + w];
          float pre = acc + gx[par][lane];
          float r = 1.f / (1.f + __expf(-pre));
          float hval = __uint_as_float((lane & 1) ? (hp & 0xffff0000u) : (hp << 16));
          float rh = r * hval;
          float other = __shfl_xor(rh, 1);
          if (!(lane & 1)){
            u64 pv = ((u64)(uint32_t)(t + 1) << 32)
                   | ((u64)f2bf(other) << 16) | (u64)f2bf(rh);
            size_t idx = (size_t)((32*g + lane) >> 1);
            #pragma unroll
            for (int rp = 0; rp < NREP; ++rp)
              astore(rhbuf + (size_t)(rp*2 + par)*HP + idx, pv);
          }
          // gates prefetch after publish: HBM latency hides under next poll
          int tn = (t + 1 < T_STEPS) ? t + 1 : t;
          gx[par ^ 1][lane] = gates[(size_t)tn*G3 + gcol] + bias;
        }
      }
    } else {
      // hop 1: h slice (for z); z-mv overlaps A's r-compute
      const u64* hsrc = hbuf + ((size_t)(rep*2 + par))*HP;
      poll_slice<false>(hsrc + wid*128, (uint32_t)t, &vph[par][wid*128], 0, lane, deadp);
      mv_pass(&vph[par][wid*128], w0, w1, red0, wid, lane);  // z partials
      // hop 2: rh slice
      const u64* rsrc = rhbuf + ((size_t)(rep*2 + par))*HP;
      poll_slice<false>(rsrc + wid*128, (uint32_t)(t + 1), &vprh[par][wid*128], 0, lane, deadp);
      mv_pass(&vprh[par][wid*128], w2, w3, red1, wid, lane); // a partials
      __syncthreads();
      if (*deadp) break;
      if (wid == 0 && lane < 32){
        float zacc = 0.f, aacc = 0.f;
        #pragma unroll
        for (int w = 0; w < 8; ++w){ zacc += red0[lane*9 + w]; aacc += red1[lane*9 + w]; }
        float z = 1.f / (1.f + __expf(-(zacc + gx[par][lane])));
        float apre = aacc + gx[par][32 + lane];
        float e = __expf(2.f*apre);
        float a = 1.f - 2.f/(1.f + e);                  // tanh, saturation-safe
        float hold = hloc[par][lane];
        float hnew = hold + z*(a - hold);               // (1-z)h + z*a
        hloc[par ^ 1][lane] = hnew;
        float other = __shfl_xor(hnew, 1);
        if (!(lane & 1)){
          u64 pv = ((u64)(uint32_t)(t + 1) << 32)
                 | ((u64)f2bf(other) << 16) | (u64)f2bf(hnew);
          size_t idx = (size_t)((32*g + lane) >> 1);
          #pragma unroll
          for (int rp = 0; rp < NREP; ++rp)
            astore(hbuf + (size_t)(rp*2 + ((t+1)&1))*HP + idx, pv);
        }
      }
      if (wid == 0 && gcol >= 0){        // prefetch z and a gate columns
        int tn = (t + 1 < T_STEPS) ? t + 1 : t;
        gx[par ^ 1][lane] = gates[(size_t)tn*G3 + gcol] + bias;
      }
    }
  }

  // T even -> final h in hloc[0]; kernel-boundary flush makes it visible
  if (!isA && tid < 32) hfinal[32*g + tid] = hloc[0][tid];
}

// ---------------- out = h_final @ w_out + b_out ----------------------------
__global__ __launch_bounds__(1024) void out_proj(const float* __restrict__ hfin,
                                                 const float* __restrict__ w_out,
                                                 const float* __restrict__ b_out,
                                                 float* __restrict__ out){
  __shared__ float red[16][80];
  const int g  = blockIdx.x;
  const int cl = threadIdx.x & 63;
  const int kc = threadIdx.x >> 6;        // 0..15
  const int col = 64*g + cl;
  float acc = 0.f;
  for (int k = kc*128; k < kc*128 + 128; ++k)
    acc = fmaf(hfin[k], w_out[(size_t)k*EOUT + col], acc);
  red[kc][cl] = acc;
  __syncthreads();
  if (kc == 0){
    float s = 0.f;
    #pragma unroll
    for (int q = 0; q < 16; ++q) s += red[q][cl];
    out[col] = s + b_out[col];
  }
}

extern "C" void kernel_launch(void* const* d_in, const int* in_sizes, int n_in,
                              void* d_out, int out_size, void* d_ws, size_t ws_size,
                              hipStream_t stream) {
  const float* x     = (const float*)d_in[0];   // (8192, 2048)
  const float* w_i   = (const float*)d_in[1];   // (2048, 6144)
  const float* w_h   = (const float*)d_in[2];   // (2048, 6144)
  const float* b     = (const float*)d_in[3];   // (6144,)
  const float* w_out = (const float*)d_in[4];   // (2048, 512)
  const float* b_out = (const float*)d_in[5];   // (512,)
  float* out = (float*)d_out;

  // Workspace: gates f32 (201.3MB) | hbuf u64[8][2][1024] | rhbuf u64[8][2][1024]
  //            | hfinal f32[2048]
  float* gates  = (float*)d_ws;
  u64*   hbuf   = (u64*)(gates + (size_t)T_STEPS * G3);
  u64*   rhbuf  = hbuf + (size_t)NREP*2*HP;
  float* hfinal = (float*)(rhbuf + (size_t)NREP*2*HP);
  (void)in_sizes; (void)n_in; (void)out_size; (void)ws_size;

  // zero tagged buffers: h_0=0 tag0 ready; rh never ready until written
  hipMemsetAsync(hbuf, 0, (size_t)(2*NREP*2*HP)*sizeof(u64), stream);

  gates_gemm<<<dim3((T_STEPS/128)*(G3/128)), dim3(512), 0, stream>>>(x, w_i, gates);

  const float* gates_c = gates;
  void* kargs[6];
  kargs[0] = (void*)&gates_c;
  kargs[1] = (void*)&w_h;
  kargs[2] = (void*)&b;
  kargs[3] = (void*)&hbuf;
  kargs[4] = (void*)&rhbuf;
  kargs[5] = (void*)&hfinal;
  hipLaunchCooperativeKernel((void*)scan_kernel, dim3(NA + NB), dim3(512), kargs, 0u, stream);

  out_proj<<<dim3(EOUT/64), dim3(1024), 0, stream>>>(hfinal, w_out, b_out, out);
}

// Round 10
// 27356.396 us; speedup vs baseline: 2.3712x; 1.0097x over previous
//
#include <hip/hip_runtime.h>
#include <stdint.h>

// Problem dims
#define T_STEPS 8192
#define DIN     2048
#define HD      2048
#define G3      6144
#define EOUT    512

// Scan partition: 64 A-blocks own 32 r-cols; 64 B-blocks own 32 z-cols +
// 32 a-cols + the h-update (z computed locally on B, off the critical path).
#define NA 64
#define NB 64
#define HP 1024          // h/rh broadcast: 1024 u64 pairs {tag | bf16 hi | bf16 lo}
#define NREP 8           // broadcast replicas
#define SPIN_MAX (1<<20)

typedef unsigned long long u64;
typedef __attribute__((ext_vector_type(8))) __bf16 bf16x8;
typedef __attribute__((ext_vector_type(8))) unsigned short u16x8;
typedef __attribute__((ext_vector_type(4))) float f32x4;

__device__ __forceinline__ uint16_t f2bf(float v){   // RNE f32->bf16
  uint32_t x = __float_as_uint(v);
  return (uint16_t)((x + 0x7fffu + ((x >> 16) & 1u)) >> 16);
}

__device__ __forceinline__ u64 aload(const u64* p){
  return __hip_atomic_load(p, __ATOMIC_RELAXED, __HIP_MEMORY_SCOPE_AGENT);
}
__device__ __forceinline__ void astore(u64* p, u64 v){
  __hip_atomic_store(p, v, __ATOMIC_RELAXED, __HIP_MEMORY_SCOPE_AGENT);
}

// A-fragment loader: lane supplies A[m = lane&15][k = kb + j], j=0..7,
// from w_h column `col` (f32, row-major, stride G3), converted to bf16.
__device__ __forceinline__ bf16x8 load_afrag(const float* __restrict__ w, int col, int kb){
  u16x8 r;
  #pragma unroll
  for (int j = 0; j < 8; ++j)
    r[j] = f2bf(w[(size_t)(kb + j)*G3 + col]);
  return __builtin_bit_cast(bf16x8, r);
}

// Wave-local tagged slice poll + LDS deposit. Each wave owns u64 elements
// [wid*128, wid*128+128) of the broadcast vector: lane takes the adjacent
// pair (2*lane, 2*lane+1) -> after tags are fresh, packs the two u32
// payloads into one ds_write_b64. If OWN=true, lanes 0..15 additionally
// poll u64 element (own_base + lane) and return it (A-finalize h values).
template<bool OWN>
__device__ __forceinline__ u64 poll_slice(const u64* src, uint32_t want,
                                          uint32_t* lds_slice, int own_base,
                                          int lane, volatile int* deadp){
  const u64* p0 = src + 2*lane;
  const u64* p1 = p0 + 1;
  const u64* po = src + own_base + lane;
  const bool need_own = OWN && (lane < 16);
  u64 v0, v1, vo = 0;
  int spins = 0;
  for(;;){
    v0 = aload(p0); v1 = aload(p1);
    if (need_own) vo = aload(po);
    bool ok = (uint32_t)(v0 >> 32) >= want && (uint32_t)(v1 >> 32) >= want &&
              (!need_own || (uint32_t)(vo >> 32) >= want);
    if (__all(ok)) break;
    if ((++spins & 63) == 0){
      if (*deadp) break;
      if (spins > SPIN_MAX){ *deadp = 1; break; }
    }
    __builtin_amdgcn_s_sleep(1);
  }
  u64 pk = ((u64)(uint32_t)v1 << 32) | (u64)(uint32_t)v0;
  *(u64*)&lds_slice[2*lane] = pk;         // wave-local; lgkmcnt orders vs reads
  return vo;
}

// One matvec pass over this wave's 256-elem k-slice: 16 MFMAs, two 16-col
// chains (wA, wB). Partials -> red[col*9 + wid]. Reads only the wave's own
// LDS slice (no cross-wave dependency -> no barrier needed before this).
__device__ __forceinline__ void mv_pass(const uint32_t* vp,
                                        const bf16x8* wA, const bf16x8* wB,
                                        float* red, int wid, int lane){
  const int boff = (lane >> 4) << 2;
  f32x4 acc0 = {0.f,0.f,0.f,0.f}, acc1 = {0.f,0.f,0.f,0.f};
  #pragma unroll
  for (int s = 0; s < 8; ++s){
    uint4 bu = *(const uint4*)(vp + s*16 + boff);
    bf16x8 bf = __builtin_bit_cast(bf16x8, bu);
    acc0 = __builtin_amdgcn_mfma_f32_16x16x32_bf16(wA[s], bf, acc0, 0, 0, 0);
    acc1 = __builtin_amdgcn_mfma_f32_16x16x32_bf16(wB[s], bf, acc1, 0, 0, 0);
  }
  if ((lane & 15) == 0){                  // D[:,0]: m = (lane>>4)*4 + r
    int mb = (lane >> 4) << 2;
    #pragma unroll
    for (int r = 0; r < 4; ++r){
      red[(mb + r)*9 + wid]      = acc0[r];
      red[(16 + mb + r)*9 + wid] = acc1[r];
    }
  }
}

// ------- gates GEMM (MFMA bf16): C[T,6144] = X[T,2048] @ Wi[2048,6144] -----
__global__ __launch_bounds__(512) void gates_gemm(const float* __restrict__ A,
                                                  const float* __restrict__ B,
                                                  float* __restrict__ C){
  __shared__ uint16_t Asb[128*40];
  __shared__ uint16_t Bsb[128*40];
  const int bm = blockIdx.x / (G3/128);
  const int bn = blockIdx.x % (G3/128);
  const int row0 = bm*128, col0 = bn*128;
  const int tid  = threadIdx.x;
  const int lane = tid & 63, wid = tid >> 6;
  const int wr = wid >> 2, wc = wid & 3;         // wave grid 2x4
  f32x4 acc[4][2] = {};
  for (int k0 = 0; k0 < DIN; k0 += 32){
    {   // stage A: [m][k] bf16
      int m = tid >> 2, ks = (tid & 3) * 8;
      const float* src = A + (size_t)(row0 + m)*DIN + k0 + ks;
      float4 f0 = *(const float4*)src;
      float4 f1 = *(const float4*)(src + 4);
      u16x8 pk;
      pk[0]=f2bf(f0.x); pk[1]=f2bf(f0.y); pk[2]=f2bf(f0.z); pk[3]=f2bf(f0.w);
      pk[4]=f2bf(f1.x); pk[5]=f2bf(f1.y); pk[6]=f2bf(f1.z); pk[7]=f2bf(f1.w);
      *(u16x8*)(Asb + m*40 + ks) = pk;
    }
    {   // stage B transposed: [n][k] bf16
      int k = tid >> 4, n8 = tid & 15;
      const float* src = B + (size_t)(k0 + k)*G3 + col0 + n8;
      #pragma unroll
      for (int i = 0; i < 8; ++i)
        Bsb[(n8 + 16*i)*40 + k] = f2bf(src[16*i]);
    }
    __syncthreads();
    const int mrow = wr*64, ncol = wc*32;
    const int fm = lane & 15, fk = (lane >> 4) * 8;
    bf16x8 bfr[2];
    #pragma unroll
    for (int j = 0; j < 2; ++j)
      bfr[j] = *(const bf16x8*)(Bsb + (ncol + j*16 + fm)*40 + fk);
    #pragma unroll
    for (int i = 0; i < 4; ++i){
      bf16x8 af = *(const bf16x8*)(Asb + (mrow + i*16 + fm)*40 + fk);
      acc[i][0] = __builtin_amdgcn_mfma_f32_16x16x32_bf16(af, bfr[0], acc[i][0], 0,0,0);
      acc[i][1] = __builtin_amdgcn_mfma_f32_16x16x32_bf16(af, bfr[1], acc[i][1], 0,0,0);
    }
    __syncthreads();
  }
  const int mrow = row0 + wr*64, ncol = col0 + wc*32;
  #pragma unroll
  for (int i = 0; i < 4; ++i)
    #pragma unroll
    for (int j = 0; j < 2; ++j){
      int cc = ncol + j*16 + (lane & 15);
      int rr = mrow + i*16 + (lane >> 4)*4;
      #pragma unroll
      for (int q = 0; q < 4; ++q)
        C[(size_t)(rr + q)*G3 + cc] = acc[i][j][q];
    }
}

// ---------------- persistent GRU scan --------------------------------------
// h_t:  hbuf [rep][t&1][1024]  {tag t   | 2x bf16}   (memset0 == h_0=0, tag 0)
// rh_t: rhbuf[rep][t&1][1024]  {tag t+1 | 2x bf16}
// Intra-block: wave-local slice poll -> deposit -> MFMA with NO barrier;
// exactly ONE __syncthreads per step (before the wave-0 finalize).
__global__ __launch_bounds__(512) void scan_kernel(
    const float* __restrict__ gates, const float* __restrict__ w_h,
    const float* __restrict__ b,
    u64* hbuf, u64* rhbuf, float* hfinal)
{
  __shared__ uint32_t vph[2][1024];    // packed h pairs
  __shared__ uint32_t vprh[2][1024];   // packed rh pairs (B only)
  __shared__ float    red0[32*9];      // A: r partials. B: z partials
  __shared__ float    red1[32*9];      // B: a partials
  __shared__ float    gx[2][64];       // x-gates (+bias): A uses 32, B 64
  __shared__ float    hloc[2][32];     // local f32 h state (B)
  __shared__ int      dead;
  volatile int* deadp = &dead;

  const int tid  = threadIdx.x;
  const int lane = tid & 63;
  const int wid  = tid >> 6;
  const bool isA = blockIdx.x < NA;
  const int  g   = isA ? (int)blockIdx.x : (int)blockIdx.x - NA;
  const int  rep = blockIdx.x & (NREP - 1);

  // Persistent weight fragments, k = wid*256 + s*32 + (lane>>4)*8 + j
  bf16x8 w0[8], w1[8], w2[8], w3[8];
  {
    const int kb0 = wid*256 + ((lane >> 4) << 3);
    const int c0  = isA ? (2048 + 32*g) : (32*g);     // A: r. B: z
    #pragma unroll
    for (int s = 0; s < 8; ++s){
      w0[s] = load_afrag(w_h, c0 + (lane & 15),      kb0 + s*32);
      w1[s] = load_afrag(w_h, c0 + 16 + (lane & 15), kb0 + s*32);
    }
    if (!isA){
      const int ca = 4096 + 32*g;
      #pragma unroll
      for (int s = 0; s < 8; ++s){
        w2[s] = load_afrag(w_h, ca + (lane & 15),      kb0 + s*32);
        w3[s] = load_afrag(w_h, ca + 16 + (lane & 15), kb0 + s*32);
      }
    }
  }

  if (tid == 0) *deadp = 0;
  if (tid < 64) ((float*)hloc)[tid] = 0.f;

  int   gcol = -1;
  float bias = 0.f;
  if (isA) { if (tid < 32) gcol = 2048 + 32*g + tid; }            // r gates
  else     { if (tid < 32)      gcol = 32*g + tid;                // z gates
             else if (tid < 64) gcol = 4096 + 32*g + (tid - 32);} // a gates
  if (gcol >= 0) { bias = b[gcol]; gx[0][tid] = gates[gcol] + bias; }
  __syncthreads();

  for (int t = 0; t < T_STEPS; ++t){
    const int par = t & 1;

    if (isA){
      // hop 1: wave-local h-slice poll+deposit; wave 0 also grabs own 16 h u64s
      const u64* src = hbuf + ((size_t)(rep*2 + par))*HP;
      u64 vo;
      if (wid == 0)
        vo = poll_slice<true >(src, (uint32_t)t, &vph[par][0],       16*g, lane, deadp);
      else
        vo = poll_slice<false>(src + wid*128, (uint32_t)t,
                               &vph[par][wid*128], 0, lane, deadp);
      mv_pass(&vph[par][wid*128], w0, w1, red0, wid, lane);  // r pre-activations
      __syncthreads();
      if (*deadp) break;
      if (wid == 0){
        // h values for rh: lane tid<32 needs payload of own-u64 (tid>>1), half (tid&1)
        uint32_t hp = __shfl((int)(uint32_t)vo, lane >> 1);
        if (lane < 32){
          float acc = 0.f;
          #pragma unroll
          for (int w = 0; w < 8; ++w) acc += red0[lane*9 + w];
          float pre = acc + gx[par][lane];
          float r = 1.f / (1.f + __expf(-pre));
          float hval = __uint_as_float((lane & 1) ? (hp & 0xffff0000u) : (hp << 16));
          float rh = r * hval;
          float other = __shfl_xor(rh, 1);
          if (!(lane & 1)){
            u64 pv = ((u64)(uint32_t)(t + 1) << 32)
                   | ((u64)f2bf(other) << 16) | (u64)f2bf(rh);
            size_t idx = (size_t)((32*g + lane) >> 1);
            #pragma unroll
            for (int rp = 0; rp < NREP; ++rp)
              astore(rhbuf + (size_t)(rp*2 + par)*HP + idx, pv);
          }
          // gates prefetch after publish: HBM latency hides under next poll
          int tn = (t + 1 < T_STEPS) ? t + 1 : t;
          gx[par ^ 1][lane] = gates[(size_t)tn*G3 + gcol] + bias;
        }
      }
    } else {
      // hop 1: h slice (for z); z-mv overlaps A's r-compute
      const u64* hsrc = hbuf + ((size_t)(rep*2 + par))*HP;
      poll_slice<false>(hsrc + wid*128, (uint32_t)t, &vph[par][wid*128], 0, lane, deadp);
      mv_pass(&vph[par][wid*128], w0, w1, red0, wid, lane);  // z partials
      // hop 2: rh slice
      const u64* rsrc = rhbuf + ((size_t)(rep*2 + par))*HP;
      poll_slice<false>(rsrc + wid*128, (uint32_t)(t + 1), &vprh[par][wid*128], 0, lane, deadp);
      mv_pass(&vprh[par][wid*128], w2, w3, red1, wid, lane); // a partials
      __syncthreads();
      if (*deadp) break;
      if (wid == 0 && lane < 32){
        float zacc = 0.f, aacc = 0.f;
        #pragma unroll
        for (int w = 0; w < 8; ++w){ zacc += red0[lane*9 + w]; aacc += red1[lane*9 + w]; }
        float z = 1.f / (1.f + __expf(-(zacc + gx[par][lane])));
        float apre = aacc + gx[par][32 + lane];
        float e = __expf(2.f*apre);
        float a = 1.f - 2.f/(1.f + e);                  // tanh, saturation-safe
        float hold = hloc[par][lane];
        float hnew = hold + z*(a - hold);               // (1-z)h + z*a
        hloc[par ^ 1][lane] = hnew;
        float other = __shfl_xor(hnew, 1);
        if (!(lane & 1)){
          u64 pv = ((u64)(uint32_t)(t + 1) << 32)
                 | ((u64)f2bf(other) << 16) | (u64)f2bf(hnew);
          size_t idx = (size_t)((32*g + lane) >> 1);
          #pragma unroll
          for (int rp = 0; rp < NREP; ++rp)
            astore(hbuf + (size_t)(rp*2 + ((t+1)&1))*HP + idx, pv);
        }
      }
      if (wid == 0 && gcol >= 0){        // prefetch z and a gate columns
        int tn = (t + 1 < T_STEPS) ? t + 1 : t;
        gx[par ^ 1][lane] = gates[(size_t)tn*G3 + gcol] + bias;
      }
    }
  }

  // T even -> final h in hloc[0]; kernel-boundary flush makes it visible
  if (!isA && tid < 32) hfinal[32*g + tid] = hloc[0][tid];
}

// ---------------- out = h_final @ w_out + b_out ----------------------------
__global__ __launch_bounds__(1024) void out_proj(const float* __restrict__ hfin,
                                                 const float* __restrict__ w_out,
                                                 const float* __restrict__ b_out,
                                                 float* __restrict__ out){
  __shared__ float red[16][80];
  const int g  = blockIdx.x;
  const int cl = threadIdx.x & 63;
  const int kc = threadIdx.x >> 6;        // 0..15
  const int col = 64*g + cl;
  float acc = 0.f;
  for (int k = kc*128; k < kc*128 + 128; ++k)
    acc = fmaf(hfin[k], w_out[(size_t)k*EOUT + col], acc);
  red[kc][cl] = acc;
  __syncthreads();
  if (kc == 0){
    float s = 0.f;
    #pragma unroll
    for (int q = 0; q < 16; ++q) s += red[q][cl];
    out[col] = s + b_out[col];
  }
}

extern "C" void kernel_launch(void* const* d_in, const int* in_sizes, int n_in,
                              void* d_out, int out_size, void* d_ws, size_t ws_size,
                              hipStream_t stream) {
  const float* x     = (const float*)d_in[0];   // (8192, 2048)
  const float* w_i   = (const float*)d_in[1];   // (2048, 6144)
  const float* w_h   = (const float*)d_in[2];   // (2048, 6144)
  const float* b     = (const float*)d_in[3];   // (6144,)
  const float* w_out = (const float*)d_in[4];   // (2048, 512)
  const float* b_out = (const float*)d_in[5];   // (512,)
  float* out = (float*)d_out;

  // Workspace: gates f32 (201.3MB) | hbuf u64[8][2][1024] | rhbuf u64[8][2][1024]
  //            | hfinal f32[2048]
  float* gates  = (float*)d_ws;
  u64*   hbuf   = (u64*)(gates + (size_t)T_STEPS * G3);
  u64*   rhbuf  = hbuf + (size_t)NREP*2*HP;
  float* hfinal = (float*)(rhbuf + (size_t)NREP*2*HP);
  (void)in_sizes; (void)n_in; (void)out_size; (void)ws_size;

  // zero tagged buffers: h_0=0 tag0 ready; rh never ready until written
  hipMemsetAsync(hbuf, 0, (size_t)(2*NREP*2*HP)*sizeof(u64), stream);

  gates_gemm<<<dim3((T_STEPS/128)*(G3/128)), dim3(512), 0, stream>>>(x, w_i, gates);

  const float* gates_c = gates;
  void* kargs[6];
  kargs[0] = (void*)&gates_c;
  kargs[1] = (void*)&w_h;
  kargs[2] = (void*)&b;
  kargs[3] = (void*)&hbuf;
  kargs[4] = (void*)&rhbuf;
  kargs[5] = (void*)&hfinal;
  hipLaunchCooperativeKernel((void*)scan_kernel, dim3(NA + NB), dim3(512), kargs, 0u, stream);

  out_proj<<<dim3(EOUT/64), dim3(1024), 0, stream>>>(hfinal, w_out, b_out, out);
}

// Round 11
// 27337.674 us; speedup vs baseline: 2.3728x; 1.0007x over previous
//
#include <hip/hip_runtime.h>
#include <stdint.h>

// Problem dims
#define T_STEPS 8192
#define DIN     2048
#define HD      2048
#define G3      6144
#define EOUT    512

// Scan partition: 64 A-blocks own 32 r-cols; 64 B-blocks own 32 z-cols +
// 32 a-cols + the h-update (z computed locally on B, off the critical path).
#define NA 64
#define NB 64
#define HP 1024          // h/rh broadcast: 1024 u64 pairs {tag | bf16 hi | bf16 lo}
#define NREP 8           // broadcast replicas
#define SPIN_MAX (1<<20)

typedef unsigned long long u64;
typedef __attribute__((ext_vector_type(8))) __bf16 bf16x8;
typedef __attribute__((ext_vector_type(8))) unsigned short u16x8;
typedef __attribute__((ext_vector_type(4))) float f32x4;

__device__ __forceinline__ uint16_t f2bf(float v){   // RNE f32->bf16
  uint32_t x = __float_as_uint(v);
  return (uint16_t)((x + 0x7fffu + ((x >> 16) & 1u)) >> 16);
}

__device__ __forceinline__ u64 aload(const u64* p){
  return __hip_atomic_load(p, __ATOMIC_RELAXED, __HIP_MEMORY_SCOPE_AGENT);
}
__device__ __forceinline__ void astore(u64* p, u64 v){
  __hip_atomic_store(p, v, __ATOMIC_RELAXED, __HIP_MEMORY_SCOPE_AGENT);
}

// A-fragment loader: lane supplies A[m = lane&15][k = kb + j], j=0..7,
// from w_h column `col` (f32, row-major, stride G3), converted to bf16.
__device__ __forceinline__ bf16x8 load_afrag(const float* __restrict__ w, int col, int kb){
  u16x8 r;
  #pragma unroll
  for (int j = 0; j < 8; ++j)
    r[j] = f2bf(w[(size_t)(kb + j)*G3 + col]);
  return __builtin_bit_cast(bf16x8, r);
}

// Wave-local tagged slice poll + LDS deposit. Each wave owns u64 elements
// [wid*128, wid*128+128) of the broadcast vector: lane takes the adjacent
// pair (2*lane, 2*lane+1) -> after tags are fresh, packs the two u32
// payloads into one ds_write_b64. If OWN=true, lanes 0..15 additionally
// poll u64 element (own_base + lane) and return it (A-finalize h values).
template<bool OWN>
__device__ __forceinline__ u64 poll_slice(const u64* src, uint32_t want,
                                          uint32_t* lds_slice, int own_base,
                                          int lane, volatile int* deadp){
  const u64* p0 = src + 2*lane;
  const u64* p1 = p0 + 1;
  const u64* po = src + own_base + lane;
  const bool need_own = OWN && (lane < 16);
  u64 v0, v1, vo = 0;
  int spins = 0;
  for(;;){
    v0 = aload(p0); v1 = aload(p1);
    if (need_own) vo = aload(po);
    bool ok = (uint32_t)(v0 >> 32) >= want && (uint32_t)(v1 >> 32) >= want &&
              (!need_own || (uint32_t)(vo >> 32) >= want);
    if (__all(ok)) break;
    if ((++spins & 63) == 0){
      if (*deadp) break;
      if (spins > SPIN_MAX){ *deadp = 1; break; }
    }
    __builtin_amdgcn_s_sleep(1);
  }
  u64 pk = ((u64)(uint32_t)v1 << 32) | (u64)(uint32_t)v0;
  *(u64*)&lds_slice[2*lane] = pk;         // wave-local; lgkmcnt orders vs reads
  return vo;
}

// One matvec pass over this wave's 256-elem k-slice: 16 MFMAs, two 16-col
// chains (wA, wB). Partials -> red[col*9 + wid]. Reads only the wave's own
// LDS slice (no cross-wave dependency -> no barrier needed before this).
__device__ __forceinline__ void mv_pass(const uint32_t* vp,
                                        const bf16x8* wA, const bf16x8* wB,
                                        float* red, int wid, int lane){
  const int boff = (lane >> 4) << 2;
  f32x4 acc0 = {0.f,0.f,0.f,0.f}, acc1 = {0.f,0.f,0.f,0.f};
  #pragma unroll
  for (int s = 0; s < 8; ++s){
    uint4 bu = *(const uint4*)(vp + s*16 + boff);
    bf16x8 bf = __builtin_bit_cast(bf16x8, bu);
    acc0 = __builtin_amdgcn_mfma_f32_16x16x32_bf16(wA[s], bf, acc0, 0, 0, 0);
    acc1 = __builtin_amdgcn_mfma_f32_16x16x32_bf16(wB[s], bf, acc1, 0, 0, 0);
  }
  if ((lane & 15) == 0){                  // D[:,0]: m = (lane>>4)*4 + r
    int mb = (lane >> 4) << 2;
    #pragma unroll
    for (int r = 0; r < 4; ++r){
      red[(mb + r)*9 + wid]      = acc0[r];
      red[(16 + mb + r)*9 + wid] = acc1[r];
    }
  }
}

// ------- gates GEMM (MFMA bf16): C[T,6144] = X[T,2048] @ Wi[2048,6144] -----
__global__ __launch_bounds__(512) void gates_gemm(const float* __restrict__ A,
                                                  const float* __restrict__ B,
                                                  float* __restrict__ C){
  __shared__ uint16_t Asb[128*40];
  __shared__ uint16_t Bsb[128*40];
  const int bm = blockIdx.x / (G3/128);
  const int bn = blockIdx.x % (G3/128);
  const int row0 = bm*128, col0 = bn*128;
  const int tid  = threadIdx.x;
  const int lane = tid & 63, wid = tid >> 6;
  const int wr = wid >> 2, wc = wid & 3;         // wave grid 2x4
  f32x4 acc[4][2] = {};
  for (int k0 = 0; k0 < DIN; k0 += 32){
    {   // stage A: [m][k] bf16
      int m = tid >> 2, ks = (tid & 3) * 8;
      const float* src = A + (size_t)(row0 + m)*DIN + k0 + ks;
      float4 f0 = *(const float4*)src;
      float4 f1 = *(const float4*)(src + 4);
      u16x8 pk;
      pk[0]=f2bf(f0.x); pk[1]=f2bf(f0.y); pk[2]=f2bf(f0.z); pk[3]=f2bf(f0.w);
      pk[4]=f2bf(f1.x); pk[5]=f2bf(f1.y); pk[6]=f2bf(f1.z); pk[7]=f2bf(f1.w);
      *(u16x8*)(Asb + m*40 + ks) = pk;
    }
    {   // stage B transposed: [n][k] bf16
      int k = tid >> 4, n8 = tid & 15;
      const float* src = B + (size_t)(k0 + k)*G3 + col0 + n8;
      #pragma unroll
      for (int i = 0; i < 8; ++i)
        Bsb[(n8 + 16*i)*40 + k] = f2bf(src[16*i]);
    }
    __syncthreads();
    const int mrow = wr*64, ncol = wc*32;
    const int fm = lane & 15, fk = (lane >> 4) * 8;
    bf16x8 bfr[2];
    #pragma unroll
    for (int j = 0; j < 2; ++j)
      bfr[j] = *(const bf16x8*)(Bsb + (ncol + j*16 + fm)*40 + fk);
    #pragma unroll
    for (int i = 0; i < 4; ++i){
      bf16x8 af = *(const bf16x8*)(Asb + (mrow + i*16 + fm)*40 + fk);
      acc[i][0] = __builtin_amdgcn_mfma_f32_16x16x32_bf16(af, bfr[0], acc[i][0], 0,0,0);
      acc[i][1] = __builtin_amdgcn_mfma_f32_16x16x32_bf16(af, bfr[1], acc[i][1], 0,0,0);
    }
    __syncthreads();
  }
  const int mrow = row0 + wr*64, ncol = col0 + wc*32;
  #pragma unroll
  for (int i = 0; i < 4; ++i)
    #pragma unroll
    for (int j = 0; j < 2; ++j){
      int cc = ncol + j*16 + (lane & 15);
      int rr = mrow + i*16 + (lane >> 4)*4;
      #pragma unroll
      for (int q = 0; q < 4; ++q)
        C[(size_t)(rr + q)*G3 + cc] = acc[i][j][q];
    }
}

// ---------------- persistent GRU scan --------------------------------------
// h_t:  hbuf [rep][t&1][1024]  {tag t   | 2x bf16}   (memset0 == h_0=0, tag 0)
// rh_t: rhbuf[rep][t&1][1024]  {tag t+1 | 2x bf16}
// Intra-block: wave-local slice poll -> deposit -> MFMA with NO barrier;
// exactly ONE __syncthreads per step (before the wave-0 finalize).
__global__ __launch_bounds__(512) void scan_kernel(
    const float* __restrict__ gates, const float* __restrict__ w_h,
    const float* __restrict__ b,
    u64* hbuf, u64* rhbuf, float* hfinal)
{
  __shared__ uint32_t vph[2][1024];    // packed h pairs
  __shared__ uint32_t vprh[2][1024];   // packed rh pairs (B only)
  __shared__ float    red0[32*9];      // A: r partials. B: z partials
  __shared__ float    red1[32*9];      // B: a partials
  __shared__ float    gx[2][64];       // x-gates (+bias): A uses 32, B 64
  __shared__ float    hloc[2][32];     // local f32 h state (B)
  __shared__ int      dead;
  volatile int* deadp = &dead;

  const int tid  = threadIdx.x;
  const int lane = tid & 63;
  const int wid  = tid >> 6;
  const bool isA = blockIdx.x < NA;
  const int  g   = isA ? (int)blockIdx.x : (int)blockIdx.x - NA;
  const int  rep = blockIdx.x & (NREP - 1);

  // Persistent weight fragments, k = wid*256 + s*32 + (lane>>4)*8 + j
  bf16x8 w0[8], w1[8], w2[8], w3[8];
  {
    const int kb0 = wid*256 + ((lane >> 4) << 3);
    const int c0  = isA ? (2048 + 32*g) : (32*g);     // A: r. B: z
    #pragma unroll
    for (int s = 0; s < 8; ++s){
      w0[s] = load_afrag(w_h, c0 + (lane & 15),      kb0 + s*32);
      w1[s] = load_afrag(w_h, c0 + 16 + (lane & 15), kb0 + s*32);
    }
    if (!isA){
      const int ca = 4096 + 32*g;
      #pragma unroll
      for (int s = 0; s < 8; ++s){
        w2[s] = load_afrag(w_h, ca + (lane & 15),      kb0 + s*32);
        w3[s] = load_afrag(w_h, ca + 16 + (lane & 15), kb0 + s*32);
      }
    }
  }

  if (tid == 0) *deadp = 0;
  if (tid < 64) ((float*)hloc)[tid] = 0.f;

  int   gcol = -1;
  float bias = 0.f;
  if (isA) { if (tid < 32) gcol = 2048 + 32*g + tid; }            // r gates
  else     { if (tid < 32)      gcol = 32*g + tid;                // z gates
             else if (tid < 64) gcol = 4096 + 32*g + (tid - 32);} // a gates
  if (gcol >= 0) { bias = b[gcol]; gx[0][tid] = gates[gcol] + bias; }
  __syncthreads();

  for (int t = 0; t < T_STEPS; ++t){
    const int par = t & 1;

    if (isA){
      // hop 1: wave-local h-slice poll+deposit; wave 0 also grabs own 16 h u64s
      const u64* src = hbuf + ((size_t)(rep*2 + par))*HP;
      u64 vo;
      if (wid == 0)
        vo = poll_slice<true >(src, (uint32_t)t, &vph[par][0],       16*g, lane, deadp);
      else
        vo = poll_slice<false>(src + wid*128, (uint32_t)t,
                               &vph[par][wid*128], 0, lane, deadp);
      mv_pass(&vph[par][wid*128], w0, w1, red0, wid, lane);  // r pre-activations
      __syncthreads();
      if (*deadp) break;
      if (wid == 0){
        // h values for rh: lane tid<32 needs payload of own-u64 (tid>>1), half (tid&1)
        uint32_t hp = __shfl((int)(uint32_t)vo, lane >> 1);
        if (lane < 32){
          float acc = 0.f;
          #pragma unroll
          for (int w = 0; w < 8; ++w) acc += red0[lane*9 + w];
          float pre = acc + gx[par][lane];
          float r = 1.f / (1.f + __expf(-pre));
          float hval = __uint_as_float((lane & 1) ? (hp & 0xffff0000u) : (hp << 16));
          float rh = r * hval;
          float other = __shfl_xor(rh, 1);
          if (!(lane & 1)){
            u64 pv = ((u64)(uint32_t)(t + 1) << 32)
                   | ((u64)f2bf(other) << 16) | (u64)f2bf(rh);
            size_t idx = (size_t)((32*g + lane) >> 1);
            #pragma unroll
            for (int rp = 0; rp < NREP; ++rp)
              astore(rhbuf + (size_t)(rp*2 + par)*HP + idx, pv);
          }
          // gates prefetch after publish: HBM latency hides under next poll
          int tn = (t + 1 < T_STEPS) ? t + 1 : t;
          gx[par ^ 1][lane] = gates[(size_t)tn*G3 + gcol] + bias;
        }
      }
    } else {
      // hop 1: h slice (for z); z-mv overlaps A's r-compute
      const u64* hsrc = hbuf + ((size_t)(rep*2 + par))*HP;
      poll_slice<false>(hsrc + wid*128, (uint32_t)t, &vph[par][wid*128], 0, lane, deadp);
      mv_pass(&vph[par][wid*128], w0, w1, red0, wid, lane);  // z partials
      // hop 2: rh slice
      const u64* rsrc = rhbuf + ((size_t)(rep*2 + par))*HP;
      poll_slice<false>(rsrc + wid*128, (uint32_t)(t + 1), &vprh[par][wid*128], 0, lane, deadp);
      mv_pass(&vprh[par][wid*128], w2, w3, red1, wid, lane); // a partials
      __syncthreads();
      if (*deadp) break;
      if (wid == 0 && lane < 32){
        float zacc = 0.f, aacc = 0.f;
        #pragma unroll
        for (int w = 0; w < 8; ++w){ zacc += red0[lane*9 + w]; aacc += red1[lane*9 + w]; }
        float z = 1.f / (1.f + __expf(-(zacc + gx[par][lane])));
        float apre = aacc + gx[par][32 + lane];
        float e = __expf(2.f*apre);
        float a = 1.f - 2.f/(1.f + e);                  // tanh, saturation-safe
        float hold = hloc[par][lane];
        float hnew = hold + z*(a - hold);               // (1-z)h + z*a
        hloc[par ^ 1][lane] = hnew;
        float other = __shfl_xor(hnew, 1);
        if (!(lane & 1)){
          u64 pv = ((u64)(uint32_t)(t + 1) << 32)
                 | ((u64)f2bf(other) << 16) | (u64)f2bf(hnew);
          size_t idx = (size_t)((32*g + lane) >> 1);
          #pragma unroll
          for (int rp = 0; rp < NREP; ++rp)
            astore(hbuf + (size_t)(rp*2 + ((t+1)&1))*HP + idx, pv);
        }
      }
      if (wid == 0 && gcol >= 0){        // prefetch z and a gate columns
        int tn = (t + 1 < T_STEPS) ? t + 1 : t;
        gx[par ^ 1][lane] = gates[(size_t)tn*G3 + gcol] + bias;
      }
    }
  }

  // T even -> final h in hloc[0]; kernel-boundary flush makes it visible
  if (!isA && tid < 32) hfinal[32*g + tid] = hloc[0][tid];
}

// ---------------- out = h_final @ w_out + b_out ----------------------------
__global__ __launch_bounds__(1024) void out_proj(const float* __restrict__ hfin,
                                                 const float* __restrict__ w_out,
                                                 const float* __restrict__ b_out,
                                                 float* __restrict__ out){
  __shared__ float red[16][80];
  const int g  = blockIdx.x;
  const int cl = threadIdx.x & 63;
  const int kc = threadIdx.x >> 6;        // 0..15
  const int col = 64*g + cl;
  float acc = 0.f;
  for (int k = kc*128; k < kc*128 + 128; ++k)
    acc = fmaf(hfin[k], w_out[(size_t)k*EOUT + col], acc);
  red[kc][cl] = acc;
  __syncthreads();
  if (kc == 0){
    float s = 0.f;
    #pragma unroll
    for (int q = 0; q < 16; ++q) s += red[q][cl];
    out[col] = s + b_out[col];
  }
}

extern "C" void kernel_launch(void* const* d_in, const int* in_sizes, int n_in,
                              void* d_out, int out_size, void* d_ws, size_t ws_size,
                              hipStream_t stream) {
  const float* x     = (const float*)d_in[0];   // (8192, 2048)
  const float* w_i   = (const float*)d_in[1];   // (2048, 6144)
  const float* w_h   = (const float*)d_in[2];   // (2048, 6144)
  const float* b     = (const float*)d_in[3];   // (6144,)
  const float* w_out = (const float*)d_in[4];   // (2048, 512)
  const float* b_out = (const float*)d_in[5];   // (512,)
  float* out = (float*)d_out;

  // Workspace: gates f32 (201.3MB) | hbuf u64[8][2][1024] | rhbuf u64[8][2][1024]
  //            | hfinal f32[2048]
  float* gates  = (float*)d_ws;
  u64*   hbuf   = (u64*)(gates + (size_t)T_STEPS * G3);
  u64*   rhbuf  = hbuf + (size_t)NREP*2*HP;
  float* hfinal = (float*)(rhbuf + (size_t)NREP*2*HP);
  (void)in_sizes; (void)n_in; (void)out_size; (void)ws_size;

  // zero tagged buffers: h_0=0 tag0 ready; rh never ready until written
  hipMemsetAsync(hbuf, 0, (size_t)(2*NREP*2*HP)*sizeof(u64), stream);

  gates_gemm<<<dim3((T_STEPS/128)*(G3/128)), dim3(512), 0, stream>>>(x, w_i, gates);

  const float* gates_c = gates;
  void* kargs[6];
  kargs[0] = (void*)&gates_c;
  kargs[1] = (void*)&w_h;
  kargs[2] = (void*)&b;
  kargs[3] = (void*)&hbuf;
  kargs[4] = (void*)&rhbuf;
  kargs[5] = (void*)&hfinal;
  hipLaunchCooperativeKernel((void*)scan_kernel, dim3(NA + NB), dim3(512), kargs, 0u, stream);

  out_proj<<<dim3(EOUT/64), dim3(1024), 0, stream>>>(hfinal, w_out, b_out, out);
}